// Round 11
// baseline (164.785 us; speedup 1.0000x reference)
//
#include <hip/hip_runtime.h>
#include <math.h>

#define NN 32768
#define KK 16
#define DD 128
#define EPSV 1e-5f

typedef __attribute__((ext_vector_type(8))) short bf16x8;
typedef __attribute__((ext_vector_type(4))) float f32x4;

__device__ __forceinline__ unsigned short f2bf(float x) {
    unsigned u; __builtin_memcpy(&u, &x, 4);
    u += 0x7fffu + ((u >> 16) & 1u);          // RNE (finite inputs)
    return (unsigned short)(u >> 16);
}
__device__ __forceinline__ float bf2f(unsigned short b) {
    unsigned u = ((unsigned)b) << 16; float f; __builtin_memcpy(&f, &u, 4); return f;
}

#define MFMA16(a, b, c) __builtin_amdgcn_mfma_f32_16x16x32_bf16((a), (b), (c), 0, 0, 0)

// LDS index swizzle for [64][128] bf16 tiles.
__device__ __forceinline__ int swz(int row, int col) {
    return row * 128 + (col ^ ((row & 7) << 3));
}

// Device-scope grid barrier; ctr zeroed by k_prep_w4 each launch sequence.
// Safe: grid is exactly 2 blocks/CU x 256 CUs, co-resident by launch bounds.
__device__ __forceinline__ void grid_barrier(int* ctr, int nblk) {
    __syncthreads();
    if (threadIdx.x == 0) {
        __hip_atomic_fetch_add(ctr, 1, __ATOMIC_ACQ_REL, __HIP_MEMORY_SCOPE_AGENT);
        while (__hip_atomic_load(ctr, __ATOMIC_ACQUIRE, __HIP_MEMORY_SCOPE_AGENT) < nblk)
            __builtin_amdgcn_s_sleep(2);
    }
    __syncthreads();
}

__device__ __forceinline__ float ld_stat(const float* p) {
    return __hip_atomic_load(p, __ATOMIC_RELAXED, __HIP_MEMORY_SCOPE_AGENT);
}

// ---------------------------------------------------------------------------
// Weight prep: 4 weight matrices -> bf16 B-fragment order; zero stats+barriers.
// Frag (s,c,lane l): elems j=0..7 = B[32s + 8*(l>>4) + j][16c + (l&15)],
// stored at out[((s*NT + c)*64 + l)*8 + j].
// ---------------------------------------------------------------------------
__global__ __launch_bounds__(256) void k_prep_w4(const float* __restrict__ W1,
                                                 const float* __restrict__ OW,
                                                 const float* __restrict__ F1W,
                                                 const float* __restrict__ F2W,
                                                 short* __restrict__ w1b,
                                                 short* __restrict__ owb,
                                                 short* __restrict__ f1wb,
                                                 short* __restrict__ f2wb,
                                                 float* __restrict__ stats) {
    int tid = blockIdx.x * 256 + threadIdx.x;
    if (tid >= 14912) return;
    if (tid >= 14336) { stats[tid - 14336] = 0.f; return; }   // 576: stats + barriers
    const float* W; short* out; int Ncol; int base;
    if (tid < 2048)       { W = W1;  out = w1b;  Ncol = 128; base = 0; }
    else if (tid < 6144)  { W = OW;  out = owb;  Ncol = 128; base = 2048; }
    else if (tid < 10240) { W = F1W; out = f1wb; Ncol = 256; base = 6144; }
    else                  { W = F2W; out = f2wb; Ncol = 128; base = 10240; }
    int t = tid - base;
    int l = t & 63, sc = t >> 6;
    int NT = Ncol >> 4;
    int c = sc % NT, s = sc / NT;
    int col = c * 16 + (l & 15);
    int k0 = s * 32 + (l >> 4) * 8;
    bf16x8 v;
    #pragma unroll
    for (int j = 0; j < 8; ++j) v[j] = (short)f2bf(W[(size_t)(k0 + j) * Ncol + col]);
    *(bf16x8*)(out + (size_t)t * 8) = v;
}

// ---------------------------------------------------------------------------
// K1: gb = bf16(h @ W1). 512 blocks x 4 waves; wave = 64 rows x 32 cols.
// ---------------------------------------------------------------------------
__global__ __launch_bounds__(256) void k_g(const float* __restrict__ h,
                                           const short* __restrict__ w1b,
                                           unsigned short* __restrict__ gb) {
    const int t = threadIdx.x, w = t >> 6, l = t & 63;
    const int g16 = l >> 4, r16 = l & 15;
    const int rowb = blockIdx.x * 64;
    f32x4 acc[4][2];
    #pragma unroll
    for (int rt = 0; rt < 4; ++rt)
        #pragma unroll
        for (int cc = 0; cc < 2; ++cc) acc[rt][cc] = (f32x4){0.f, 0.f, 0.f, 0.f};
    #pragma unroll
    for (int s = 0; s < 4; ++s) {
        bf16x8 a[4];
        #pragma unroll
        for (int rt = 0; rt < 4; ++rt) {
            const float* hp = h + (size_t)(rowb + rt * 16 + r16) * DD + s * 32 + g16 * 8;
            float4 x0 = *(const float4*)hp;
            float4 x1 = *(const float4*)(hp + 4);
            bf16x8 af;
            af[0] = (short)f2bf(x0.x); af[1] = (short)f2bf(x0.y);
            af[2] = (short)f2bf(x0.z); af[3] = (short)f2bf(x0.w);
            af[4] = (short)f2bf(x1.x); af[5] = (short)f2bf(x1.y);
            af[6] = (short)f2bf(x1.z); af[7] = (short)f2bf(x1.w);
            a[rt] = af;
        }
        #pragma unroll
        for (int cc = 0; cc < 2; ++cc) {
            bf16x8 b = *(const bf16x8*)(w1b + ((size_t)(s * 8 + w * 2 + cc) * 64 + l) * 8);
            #pragma unroll
            for (int rt = 0; rt < 4; ++rt) acc[rt][cc] = MFMA16(a[rt], b, acc[rt][cc]);
        }
    }
    #pragma unroll
    for (int cc = 0; cc < 2; ++cc) {
        int col = (w * 2 + cc) * 16 + r16;
        #pragma unroll
        for (int rt = 0; rt < 4; ++rt)
            #pragma unroll
            for (int j = 0; j < 4; ++j)
                gb[(size_t)(rowb + rt * 16 + g16 * 4 + j) * DD + col] = f2bf(acc[rt][cc][j]);
    }
}

// ---------------------------------------------------------------------------
// K2: per-node attention stats. One wave per node, 16-lane groups.
// ---------------------------------------------------------------------------
__global__ __launch_bounds__(256) void k_att(const unsigned short* __restrict__ gb,
                                             const int* __restrict__ nbr,
                                             const float* __restrict__ b1,
                                             const float* __restrict__ W2,
                                             const float* __restrict__ b2,
                                             float* __restrict__ amean,
                                             float* __restrict__ amaxv,
                                             float* __restrict__ aminv) {
    const int t = threadIdx.x;
    const int w = t >> 6, lane = t & 63;
    const int node = blockIdx.x * 4 + w;
    const int grp = lane >> 4, r = lane & 15;

    bf16x8 gd8 = *(const bf16x8*)((const short*)gb + (size_t)node * DD + r * 8);
    float gd[8];
    #pragma unroll
    for (int j = 0; j < 8; ++j) gd[j] = bf2f((unsigned short)gd8[j]);
    float4 b1a = *(const float4*)(b1 + r * 8);
    float4 b1b = *(const float4*)(b1 + r * 8 + 4);
    float4 w2a = *(const float4*)(W2 + r * 8);
    float4 w2b = *(const float4*)(W2 + r * 8 + 4);
    const float b1v[8] = {b1a.x, b1a.y, b1a.z, b1a.w, b1b.x, b1b.y, b1b.z, b1b.w};
    const float w2v[8] = {w2a.x, w2a.y, w2a.z, w2a.w, w2b.x, w2b.y, w2b.z, w2b.w};
    const float b2s = b2[0];

    int4 nb4 = *(const int4*)(nbr + node * KK + grp * 4);
    const int srcs[4] = {nb4.x, nb4.y, nb4.z, nb4.w};

    float asum = 0.f, amx = -1e30f, amn = 1e30f;
    #pragma unroll
    for (int it = 0; it < 4; ++it) {
        bf16x8 gs8 = *(const bf16x8*)((const short*)gb + (size_t)srcs[it] * DD + r * 8);
        float v = 0.f;
        #pragma unroll
        for (int j = 0; j < 8; ++j)
            v += fmaxf(bf2f((unsigned short)gs8[j]) - gd[j] + b1v[j], 0.f) * w2v[j];
        v += __shfl_xor(v, 1); v += __shfl_xor(v, 2);
        v += __shfl_xor(v, 4); v += __shfl_xor(v, 8);
        float s = fmaxf(v + b2s, 0.f);
        float att = __expf(-s);
        asum += att;
        amx = fmaxf(amx, att);
        amn = fminf(amn, att);
    }
    asum += __shfl_xor(asum, 16); asum += __shfl_xor(asum, 32);
    amx = fmaxf(amx, __shfl_xor(amx, 16)); amx = fmaxf(amx, __shfl_xor(amx, 32));
    amn = fminf(amn, __shfl_xor(amn, 16)); amn = fminf(amn, __shfl_xor(amn, 32));
    if (lane == 0) {
        amean[node] = asum * (1.f / KK);
        amaxv[node] = amx;
        aminv[node] = amn;
    }
}

// ---------------------------------------------------------------------------
// K3 (persistent, 512 blocks = 2/CU, two in-kernel grid barriers):
//  T:   t = h + [am*h || sel*h] @ OW + Ob -> t_lds (bf16); bn1 atomics
//  bar1; x-frags = bn1(t) once; FFN1 -> u_lds half; FFN2 acc2; z in regs;
//  bn2 atomics; bar2; OUT: out = bn2(z).
// ---------------------------------------------------------------------------
__global__ __launch_bounds__(256, 2) void k_fused(const short* __restrict__ owb,
                                                  const float* __restrict__ h,
                                                  const float* __restrict__ Ob,
                                                  const float* __restrict__ amean,
                                                  const float* __restrict__ amaxv,
                                                  const float* __restrict__ aminv,
                                                  const short* __restrict__ f1wb,
                                                  const float* __restrict__ F1b,
                                                  const short* __restrict__ f2wb,
                                                  const float* __restrict__ F2b,
                                                  const float* __restrict__ bn1g,
                                                  const float* __restrict__ bn1b,
                                                  const float* __restrict__ bn2g,
                                                  const float* __restrict__ bn2b,
                                                  float* __restrict__ stats,
                                                  float* __restrict__ out) {
    __shared__ unsigned short t_lds[64 * 128];   // 16 KB (t, bf16 swizzled)
    __shared__ unsigned short u_lds[64 * 128];   // 16 KB (one column-half of u)
    __shared__ float sc_l[128], sh_l[128];

    float* bnsum1 = stats;
    float* bnsq1  = stats + 128;
    float* bnsum2 = stats + 256;
    float* bnsq2  = stats + 384;
    int*   bar    = (int*)(stats + 512);

    const int t = threadIdx.x, w = t >> 6, l = t & 63;
    const int g16 = l >> 4, r16 = l & 15;
    const int rowb = blockIdx.x * 64;
    const float inv = 1.f / NN;
    const int nblk = gridDim.x;

    // ---------------- Phase T ----------------
    {
        float am[4], ax[4], an[4];
        #pragma unroll
        for (int rt = 0; rt < 4; ++rt) {
            int row = rowb + rt * 16 + r16;
            am[rt] = amean[row]; ax[rt] = amaxv[row]; an[rt] = aminv[row];
        }
        f32x4 acc[4][2];
        #pragma unroll
        for (int rt = 0; rt < 4; ++rt)
            #pragma unroll
            for (int cc = 0; cc < 2; ++cc) acc[rt][cc] = (f32x4){0.f, 0.f, 0.f, 0.f};
        #pragma unroll
        for (int s = 0; s < 4; ++s) {
            bf16x8 aM[4], aS[4];
            #pragma unroll
            for (int rt = 0; rt < 4; ++rt) {
                const float* hp = h + (size_t)(rowb + rt * 16 + r16) * DD + s * 32 + g16 * 8;
                float4 x0 = *(const float4*)hp;
                float4 x1 = *(const float4*)(hp + 4);
                float v[8] = {x0.x, x0.y, x0.z, x0.w, x1.x, x1.y, x1.z, x1.w};
                bf16x8 m, sfr;
                #pragma unroll
                for (int j = 0; j < 8; ++j) {
                    m[j]   = (short)f2bf(am[rt] * v[j]);
                    sfr[j] = (short)f2bf((v[j] >= 0.f ? ax[rt] : an[rt]) * v[j]);
                }
                aM[rt] = m; aS[rt] = sfr;
            }
            #pragma unroll
            for (int cc = 0; cc < 2; ++cc) {
                bf16x8 bM = *(const bf16x8*)(owb + ((size_t)(s * 8 + w * 2 + cc) * 64 + l) * 8);
                bf16x8 bS = *(const bf16x8*)(owb + ((size_t)((s + 4) * 8 + w * 2 + cc) * 64 + l) * 8);
                #pragma unroll
                for (int rt = 0; rt < 4; ++rt) {
                    acc[rt][cc] = MFMA16(aM[rt], bM, acc[rt][cc]);
                    acc[rt][cc] = MFMA16(aS[rt], bS, acc[rt][cc]);
                }
            }
        }
        #pragma unroll
        for (int cc = 0; cc < 2; ++cc) {
            int col = (w * 2 + cc) * 16 + r16;
            float ob = Ob[col];
            float cs = 0.f, cq = 0.f;
            #pragma unroll
            for (int rt = 0; rt < 4; ++rt)
                #pragma unroll
                for (int j = 0; j < 4; ++j) {
                    int lr = rt * 16 + g16 * 4 + j;
                    float tv = h[(size_t)(rowb + lr) * DD + col] + acc[rt][cc][j] + ob;
                    t_lds[swz(lr, col)] = f2bf(tv);
                    cs += tv; cq += tv * tv;
                }
            cs += __shfl_xor(cs, 16); cs += __shfl_xor(cs, 32);
            cq += __shfl_xor(cq, 16); cq += __shfl_xor(cq, 32);
            if (g16 == 0) {
                atomicAdd(&bnsum1[col], cs);
                atomicAdd(&bnsq1[col], cq);
            }
        }
    }

    grid_barrier(&bar[0], nblk);

    // ---------------- Phase FFN ----------------
    if (t < 128) {
        float s = ld_stat(&bnsum1[t]), q = ld_stat(&bnsq1[t]);
        float mu = s * inv;
        float var = q * inv - mu * mu;
        float sc = bn1g[t] * rsqrtf(var + EPSV);
        sc_l[t] = sc;
        sh_l[t] = bn1b[t] - mu * sc;
    }
    __syncthreads();

    // build x = bn1(t) A-frags once (16 frags: s x rt)
    bf16x8 a_x[4][4];
    #pragma unroll
    for (int s = 0; s < 4; ++s) {
        int k0 = s * 32 + g16 * 8;
        float scv[8], shv[8];
        #pragma unroll
        for (int j = 0; j < 8; ++j) { scv[j] = sc_l[k0 + j]; shv[j] = sh_l[k0 + j]; }
        #pragma unroll
        for (int rt = 0; rt < 4; ++rt) {
            bf16x8 tv8 = *(const bf16x8*)&t_lds[swz(rt * 16 + r16, k0)];
            bf16x8 af;
            #pragma unroll
            for (int j = 0; j < 8; ++j)
                af[j] = (short)f2bf(bf2f((unsigned short)tv8[j]) * scv[j] + shv[j]);
            a_x[s][rt] = af;
        }
    }

    f32x4 acc2[4][2];
    #pragma unroll
    for (int rt = 0; rt < 4; ++rt)
        #pragma unroll
        for (int cc = 0; cc < 2; ++cc) acc2[rt][cc] = (f32x4){0.f, 0.f, 0.f, 0.f};

    #pragma unroll 1
    for (int ct = 0; ct < 2; ++ct) {
        f32x4 acc1[4][2];
        #pragma unroll
        for (int rt = 0; rt < 4; ++rt)
            #pragma unroll
            for (int cc = 0; cc < 2; ++cc) acc1[rt][cc] = (f32x4){0.f, 0.f, 0.f, 0.f};
        #pragma unroll
        for (int s = 0; s < 4; ++s)
            #pragma unroll
            for (int cc = 0; cc < 2; ++cc) {
                int fc = ct * 8 + w * 2 + cc;
                bf16x8 b = *(const bf16x8*)(f1wb + ((size_t)(s * 16 + fc) * 64 + l) * 8);
                #pragma unroll
                for (int rt = 0; rt < 4; ++rt) acc1[rt][cc] = MFMA16(a_x[s][rt], b, acc1[rt][cc]);
            }
        #pragma unroll
        for (int cc = 0; cc < 2; ++cc) {
            int colh = (w * 2 + cc) * 16 + r16;
            float fb = F1b[ct * 128 + colh];
            #pragma unroll
            for (int rt = 0; rt < 4; ++rt)
                #pragma unroll
                for (int j = 0; j < 4; ++j)
                    u_lds[swz(rt * 16 + g16 * 4 + j, colh)] =
                        f2bf(fmaxf(acc1[rt][cc][j] + fb, 0.f));
        }
        __syncthreads();
        #pragma unroll
        for (int ks = 0; ks < 4; ++ks) {
            bf16x8 a2[4];
            #pragma unroll
            for (int rt = 0; rt < 4; ++rt)
                a2[rt] = *(const bf16x8*)&u_lds[swz(rt * 16 + r16, ks * 32 + g16 * 8)];
            int sg = ct * 4 + ks;
            #pragma unroll
            for (int cc = 0; cc < 2; ++cc) {
                bf16x8 b = *(const bf16x8*)(f2wb + ((size_t)(sg * 8 + w * 2 + cc) * 64 + l) * 8);
                #pragma unroll
                for (int rt = 0; rt < 4; ++rt) acc2[rt][cc] = MFMA16(a2[rt], b, acc2[rt][cc]);
            }
        }
        __syncthreads();  // protect u_lds WAR before next half
    }

    // z = x + acc2 + F2b (kept in acc2); bn2 column sums
    #pragma unroll
    for (int cc = 0; cc < 2; ++cc) {
        int col = (w * 2 + cc) * 16 + r16;
        float fb = F2b[col];
        float sc1c = sc_l[col], sh1c = sh_l[col];
        float cs = 0.f, cq = 0.f;
        #pragma unroll
        for (int rt = 0; rt < 4; ++rt)
            #pragma unroll
            for (int j = 0; j < 4; ++j) {
                int lr = rt * 16 + g16 * 4 + j;
                float xv = bf2f(t_lds[swz(lr, col)]) * sc1c + sh1c;
                float zv = xv + acc2[rt][cc][j] + fb;
                acc2[rt][cc][j] = zv;
                cs += zv; cq += zv * zv;
            }
        cs += __shfl_xor(cs, 16); cs += __shfl_xor(cs, 32);
        cq += __shfl_xor(cq, 16); cq += __shfl_xor(cq, 32);
        if (g16 == 0) {
            atomicAdd(&bnsum2[col], cs);
            atomicAdd(&bnsq2[col], cq);
        }
    }

    grid_barrier(&bar[1], nblk);

    // ---------------- Phase OUT ----------------
    #pragma unroll
    for (int cc = 0; cc < 2; ++cc) {
        int col = (w * 2 + cc) * 16 + r16;
        float s = ld_stat(&bnsum2[col]), q = ld_stat(&bnsq2[col]);
        float mu = s * inv;
        float var = q * inv - mu * mu;
        float sc2 = bn2g[col] * rsqrtf(var + EPSV);
        float sh2 = bn2b[col] - mu * sc2;
        #pragma unroll
        for (int rt = 0; rt < 4; ++rt)
            #pragma unroll
            for (int j = 0; j < 4; ++j) {
                int lr = rt * 16 + g16 * 4 + j;
                out[(size_t)(rowb + lr) * DD + col] = acc2[rt][cc][j] * sc2 + sh2;
            }
    }
}

// ---------------------------------------------------------------------------
extern "C" void kernel_launch(void* const* d_in, const int* in_sizes, int n_in,
                              void* d_out, int out_size, void* d_ws, size_t ws_size,
                              hipStream_t stream) {
    const float* h    = (const float*)d_in[0];
    const int*   nbr  = (const int*)d_in[1];
    const float* W1   = (const float*)d_in[2];
    const float* b1   = (const float*)d_in[3];
    const float* W2   = (const float*)d_in[4];
    const float* b2   = (const float*)d_in[5];
    const float* OW   = (const float*)d_in[6];
    const float* Ob   = (const float*)d_in[7];
    const float* bn1g = (const float*)d_in[8];
    const float* bn1b = (const float*)d_in[9];
    const float* F1W  = (const float*)d_in[10];
    const float* F1b  = (const float*)d_in[11];
    const float* F2W  = (const float*)d_in[12];
    const float* F2b  = (const float*)d_in[13];
    const float* bn2g = (const float*)d_in[14];
    const float* bn2b = (const float*)d_in[15];
    float* out = (float*)d_out;

    char* wsb = (char*)d_ws;
    unsigned short* gb = (unsigned short*)wsb;                        // 8 MB bf16
    char* wtb = wsb + ((size_t)8 << 20);
    short* w1b  = (short*)wtb;                                        // 32 KB
    short* owb  = w1b + 16384;                                        // 64 KB
    short* f1wb = owb + 32768;                                        // 64 KB
    short* f2wb = f1wb + 32768;                                       // 64 KB
    float* stats = (float*)(f2wb + 32768);   // 512 stats + 64 barrier/pad
    float* amean  = stats + 576;             // N floats
    float* amaxv  = amean + NN;              // N floats
    float* aminv  = amaxv + NN;              // N floats

    k_prep_w4<<<59, 256, 0, stream>>>(W1, OW, F1W, F2W, w1b, owb, f1wb, f2wb, stats);
    k_g<<<NN / 64, 256, 0, stream>>>(h, w1b, gb);
    k_att<<<NN / 4, 256, 0, stream>>>(gb, nbr, b1, W2, b2, amean, amaxv, aminv);
    k_fused<<<NN / 64, 256, 0, stream>>>((const short*)owb, h, Ob, amean, amaxv, aminv,
                                         (const short*)f1wb, F1b, (const short*)f2wb, F2b,
                                         bn1g, bn1b, bn2g, bn2b, stats, out);
}

// Round 12
// 88.862 us; speedup vs baseline: 1.8544x; 1.8544x over previous
//
#include <hip/hip_runtime.h>
#include <math.h>

#define NN 32768
#define KK 16
#define DD 128
#define EPSV 1e-5f

typedef __attribute__((ext_vector_type(8))) short bf16x8;
typedef __attribute__((ext_vector_type(4))) float f32x4;

__device__ __forceinline__ unsigned short f2bf(float x) {
    unsigned u; __builtin_memcpy(&u, &x, 4);
    u += 0x7fffu + ((u >> 16) & 1u);          // RNE (finite inputs)
    return (unsigned short)(u >> 16);
}
__device__ __forceinline__ float bf2f(unsigned short b) {
    unsigned u = ((unsigned)b) << 16; float f; __builtin_memcpy(&f, &u, 4); return f;
}

#define MFMA16(a, b, c) __builtin_amdgcn_mfma_f32_16x16x32_bf16((a), (b), (c), 0, 0, 0)

// LDS index swizzle for [64][128] bf16 tiles: flip ushort-index bits 3..5
// with row&7 so strided row reads spread across banks.
__device__ __forceinline__ int swz(int row, int col) {
    return row * 128 + (col ^ ((row & 7) << 3));
}

// ---------------------------------------------------------------------------
// Weight prep: 4 weight matrices -> bf16 B-fragment order; also zero stats.
// Frag (s,c,lane l): elems j=0..7 = B[32s + 8*(l>>4) + j][16c + (l&15)],
// stored at out[((s*NT + c)*64 + l)*8 + j].
// ---------------------------------------------------------------------------
__global__ __launch_bounds__(256) void k_prep_w4(const float* __restrict__ W1,
                                                 const float* __restrict__ OW,
                                                 const float* __restrict__ F1W,
                                                 const float* __restrict__ F2W,
                                                 short* __restrict__ w1b,
                                                 short* __restrict__ owb,
                                                 short* __restrict__ f1wb,
                                                 short* __restrict__ f2wb,
                                                 float* __restrict__ stats) {
    int tid = blockIdx.x * 256 + threadIdx.x;
    if (tid >= 14848) return;
    if (tid >= 14336) { stats[tid - 14336] = 0.f; return; }
    const float* W; short* out; int Ncol; int base;
    if (tid < 2048)       { W = W1;  out = w1b;  Ncol = 128; base = 0; }
    else if (tid < 6144)  { W = OW;  out = owb;  Ncol = 128; base = 2048; }
    else if (tid < 10240) { W = F1W; out = f1wb; Ncol = 256; base = 6144; }
    else                  { W = F2W; out = f2wb; Ncol = 128; base = 10240; }
    int t = tid - base;
    int l = t & 63, sc = t >> 6;
    int NT = Ncol >> 4;
    int c = sc % NT, s = sc / NT;
    int col = c * 16 + (l & 15);
    int k0 = s * 32 + (l >> 4) * 8;
    bf16x8 v;
    #pragma unroll
    for (int j = 0; j < 8; ++j) v[j] = (short)f2bf(W[(size_t)(k0 + j) * Ncol + col]);
    *(bf16x8*)(out + (size_t)t * 8) = v;
}

// ---------------------------------------------------------------------------
// K1: gb = bf16(h @ W1). 512 blocks x 4 waves; wave = 64 rows x 32 cols.
// ---------------------------------------------------------------------------
__global__ __launch_bounds__(256) void k_g(const float* __restrict__ h,
                                           const short* __restrict__ w1b,
                                           unsigned short* __restrict__ gb) {
    const int t = threadIdx.x, w = t >> 6, l = t & 63;
    const int g16 = l >> 4, r16 = l & 15;
    const int rowb = blockIdx.x * 64;
    f32x4 acc[4][2];
    #pragma unroll
    for (int rt = 0; rt < 4; ++rt)
        #pragma unroll
        for (int cc = 0; cc < 2; ++cc) acc[rt][cc] = (f32x4){0.f, 0.f, 0.f, 0.f};
    #pragma unroll
    for (int s = 0; s < 4; ++s) {
        bf16x8 a[4];
        #pragma unroll
        for (int rt = 0; rt < 4; ++rt) {
            const float* hp = h + (size_t)(rowb + rt * 16 + r16) * DD + s * 32 + g16 * 8;
            float4 x0 = *(const float4*)hp;
            float4 x1 = *(const float4*)(hp + 4);
            bf16x8 af;
            af[0] = (short)f2bf(x0.x); af[1] = (short)f2bf(x0.y);
            af[2] = (short)f2bf(x0.z); af[3] = (short)f2bf(x0.w);
            af[4] = (short)f2bf(x1.x); af[5] = (short)f2bf(x1.y);
            af[6] = (short)f2bf(x1.z); af[7] = (short)f2bf(x1.w);
            a[rt] = af;
        }
        #pragma unroll
        for (int cc = 0; cc < 2; ++cc) {
            bf16x8 b = *(const bf16x8*)(w1b + ((size_t)(s * 8 + w * 2 + cc) * 64 + l) * 8);
            #pragma unroll
            for (int rt = 0; rt < 4; ++rt) acc[rt][cc] = MFMA16(a[rt], b, acc[rt][cc]);
        }
    }
    #pragma unroll
    for (int cc = 0; cc < 2; ++cc) {
        int col = (w * 2 + cc) * 16 + r16;
        #pragma unroll
        for (int rt = 0; rt < 4; ++rt)
            #pragma unroll
            for (int j = 0; j < 4; ++j)
                gb[(size_t)(rowb + rt * 16 + g16 * 4 + j) * DD + col] = f2bf(acc[rt][cc][j]);
    }
}

// ---------------------------------------------------------------------------
// K2: per-node attention stats. One wave per node, 16-lane groups.
// ---------------------------------------------------------------------------
__global__ __launch_bounds__(256) void k_att(const unsigned short* __restrict__ gb,
                                             const int* __restrict__ nbr,
                                             const float* __restrict__ b1,
                                             const float* __restrict__ W2,
                                             const float* __restrict__ b2,
                                             float* __restrict__ amean,
                                             float* __restrict__ amaxv,
                                             float* __restrict__ aminv) {
    const int t = threadIdx.x;
    const int w = t >> 6, lane = t & 63;
    const int node = blockIdx.x * 4 + w;
    const int grp = lane >> 4, r = lane & 15;

    bf16x8 gd8 = *(const bf16x8*)((const short*)gb + (size_t)node * DD + r * 8);
    float gd[8];
    #pragma unroll
    for (int j = 0; j < 8; ++j) gd[j] = bf2f((unsigned short)gd8[j]);
    float4 b1a = *(const float4*)(b1 + r * 8);
    float4 b1b = *(const float4*)(b1 + r * 8 + 4);
    float4 w2a = *(const float4*)(W2 + r * 8);
    float4 w2b = *(const float4*)(W2 + r * 8 + 4);
    const float b1v[8] = {b1a.x, b1a.y, b1a.z, b1a.w, b1b.x, b1b.y, b1b.z, b1b.w};
    const float w2v[8] = {w2a.x, w2a.y, w2a.z, w2a.w, w2b.x, w2b.y, w2b.z, w2b.w};
    const float b2s = b2[0];

    int4 nb4 = *(const int4*)(nbr + node * KK + grp * 4);
    const int srcs[4] = {nb4.x, nb4.y, nb4.z, nb4.w};

    float asum = 0.f, amx = -1e30f, amn = 1e30f;
    #pragma unroll
    for (int it = 0; it < 4; ++it) {
        bf16x8 gs8 = *(const bf16x8*)((const short*)gb + (size_t)srcs[it] * DD + r * 8);
        float v = 0.f;
        #pragma unroll
        for (int j = 0; j < 8; ++j)
            v += fmaxf(bf2f((unsigned short)gs8[j]) - gd[j] + b1v[j], 0.f) * w2v[j];
        v += __shfl_xor(v, 1); v += __shfl_xor(v, 2);
        v += __shfl_xor(v, 4); v += __shfl_xor(v, 8);
        float s = fmaxf(v + b2s, 0.f);
        float att = __expf(-s);
        asum += att;
        amx = fmaxf(amx, att);
        amn = fminf(amn, att);
    }
    asum += __shfl_xor(asum, 16); asum += __shfl_xor(asum, 32);
    amx = fmaxf(amx, __shfl_xor(amx, 16)); amx = fmaxf(amx, __shfl_xor(amx, 32));
    amn = fminf(amn, __shfl_xor(amn, 16)); amn = fminf(amn, __shfl_xor(amn, 32));
    if (lane == 0) {
        amean[node] = asum * (1.f / KK);
        amaxv[node] = amx;
        aminv[node] = amn;
    }
}

// ---------------------------------------------------------------------------
// K3: t = h + [am*h || sel*h] @ OW + Ob; A-frags built on the fly from h.
// t stored BF16; fused bn1 column sums. 512 blocks x 4 waves, wave = 64x32.
// ---------------------------------------------------------------------------
__global__ __launch_bounds__(256) void k_t(const short* __restrict__ owb,
                                           const float* __restrict__ h,
                                           const float* __restrict__ Ob,
                                           const float* __restrict__ amean,
                                           const float* __restrict__ amaxv,
                                           const float* __restrict__ aminv,
                                           unsigned short* __restrict__ tb,
                                           float* __restrict__ bnsum,
                                           float* __restrict__ bnsq) {
    const int t = threadIdx.x, w = t >> 6, l = t & 63;
    const int g16 = l >> 4, r16 = l & 15;
    const int rowb = blockIdx.x * 64;

    float am[4], ax[4], an[4];
    #pragma unroll
    for (int rt = 0; rt < 4; ++rt) {
        int row = rowb + rt * 16 + r16;
        am[rt] = amean[row]; ax[rt] = amaxv[row]; an[rt] = aminv[row];
    }

    f32x4 acc[4][2];
    #pragma unroll
    for (int rt = 0; rt < 4; ++rt)
        #pragma unroll
        for (int cc = 0; cc < 2; ++cc) acc[rt][cc] = (f32x4){0.f, 0.f, 0.f, 0.f};

    #pragma unroll
    for (int s = 0; s < 4; ++s) {
        bf16x8 aM[4], aS[4];
        #pragma unroll
        for (int rt = 0; rt < 4; ++rt) {
            const float* hp = h + (size_t)(rowb + rt * 16 + r16) * DD + s * 32 + g16 * 8;
            float4 x0 = *(const float4*)hp;
            float4 x1 = *(const float4*)(hp + 4);
            float v[8] = {x0.x, x0.y, x0.z, x0.w, x1.x, x1.y, x1.z, x1.w};
            bf16x8 m, sfr;
            #pragma unroll
            for (int j = 0; j < 8; ++j) {
                m[j]   = (short)f2bf(am[rt] * v[j]);
                sfr[j] = (short)f2bf((v[j] >= 0.f ? ax[rt] : an[rt]) * v[j]);
            }
            aM[rt] = m; aS[rt] = sfr;
        }
        #pragma unroll
        for (int cc = 0; cc < 2; ++cc) {
            bf16x8 bM = *(const bf16x8*)(owb + ((size_t)(s * 8 + w * 2 + cc) * 64 + l) * 8);
            bf16x8 bS = *(const bf16x8*)(owb + ((size_t)((s + 4) * 8 + w * 2 + cc) * 64 + l) * 8);
            #pragma unroll
            for (int rt = 0; rt < 4; ++rt) {
                acc[rt][cc] = MFMA16(aM[rt], bM, acc[rt][cc]);
                acc[rt][cc] = MFMA16(aS[rt], bS, acc[rt][cc]);
            }
        }
    }

    #pragma unroll
    for (int cc = 0; cc < 2; ++cc) {
        int col = (w * 2 + cc) * 16 + r16;
        float ob = Ob[col];
        float cs = 0.f, cq = 0.f;
        #pragma unroll
        for (int rt = 0; rt < 4; ++rt)
            #pragma unroll
            for (int j = 0; j < 4; ++j) {
                int row = rowb + rt * 16 + g16 * 4 + j;
                size_t idx = (size_t)row * DD + col;
                float tv = h[idx] + acc[rt][cc][j] + ob;
                tb[idx] = f2bf(tv);
                cs += tv; cq += tv * tv;
            }
        cs += __shfl_xor(cs, 16); cs += __shfl_xor(cs, 32);
        cq += __shfl_xor(cq, 16); cq += __shfl_xor(cq, 32);
        if (g16 == 0) {
            atomicAdd(&bnsum[col], cs);
            atomicAdd(&bnsq[col], cq);
        }
    }
}

// ---------------------------------------------------------------------------
// K4: fused FFN1+FFN2. 512 blocks x 8 waves (512 thr), 64 rows/block.
//   phase0: sc/sh(bn1) table -> LDS
//   phase1: x = bn1(t) bf16 -> x_lds (swizzled)
//   per column-half: FFN1 (wave = 64x16) -> u half in LDS
//                    -> acc2 += u @ F2W-half (wave = 64x16)
//   epilogue: z = x + acc2 + F2b -> global (bf16); bn2 sums via shfl+atomics.
// ---------------------------------------------------------------------------
__global__ __launch_bounds__(512) void k_ffn12(const unsigned short* __restrict__ tb,
                                               const short* __restrict__ f1wb,
                                               const float* __restrict__ F1b,
                                               const short* __restrict__ f2wb,
                                               const float* __restrict__ F2b,
                                               const float* __restrict__ bn1g,
                                               const float* __restrict__ bn1b,
                                               const float* __restrict__ bnsum1,
                                               const float* __restrict__ bnsq1,
                                               unsigned short* __restrict__ zb,
                                               float* __restrict__ bnsum2,
                                               float* __restrict__ bnsq2) {
    __shared__ unsigned short x_lds[64 * 128];   // 16 KB  (x = bn1(t), bf16)
    __shared__ unsigned short u_lds[64 * 128];   // 16 KB  (one column-half of u)
    __shared__ float sc_l[128], sh_l[128];

    const int t = threadIdx.x, w = t >> 6, l = t & 63;
    const int g16 = l >> 4, r16 = l & 15;
    const int rowb = blockIdx.x * 64;
    const float inv = 1.f / NN;

    // phase0: bn1 scale/shift per column
    if (t < 128) {
        float mu = bnsum1[t] * inv;
        float var = bnsq1[t] * inv - mu * mu;
        float sc = bn1g[t] * rsqrtf(var + EPSV);
        sc_l[t] = sc;
        sh_l[t] = bn1b[t] - mu * sc;
    }
    __syncthreads();

    // phase1: stage x = bn1(t) into LDS (each thread: 1 row, 16 cols)
    {
        int row = t >> 3, c0 = (t & 7) * 16;
        #pragma unroll
        for (int i = 0; i < 2; ++i) {
            int c = c0 + i * 8;
            bf16x8 v = *(const bf16x8*)(tb + (size_t)(rowb + row) * DD + c);
            bf16x8 xv;
            #pragma unroll
            for (int j = 0; j < 8; ++j)
                xv[j] = (short)f2bf(bf2f((unsigned short)v[j]) * sc_l[c + j] + sh_l[c + j]);
            *(bf16x8*)&x_lds[swz(row, c)] = xv;
        }
    }
    __syncthreads();

    f32x4 acc2[4];
    #pragma unroll
    for (int rt = 0; rt < 4; ++rt) acc2[rt] = (f32x4){0.f, 0.f, 0.f, 0.f};

    #pragma unroll 1
    for (int ct = 0; ct < 2; ++ct) {
        // FFN1: u_half(64x128); wave w computes 64 rows x cols [w*16, w*16+16)
        f32x4 acc1[4];
        #pragma unroll
        for (int rt = 0; rt < 4; ++rt) acc1[rt] = (f32x4){0.f, 0.f, 0.f, 0.f};
        #pragma unroll
        for (int s = 0; s < 4; ++s) {
            bf16x8 a[4];
            #pragma unroll
            for (int rt = 0; rt < 4; ++rt)
                a[rt] = *(const bf16x8*)&x_lds[swz(rt * 16 + r16, s * 32 + g16 * 8)];
            int fc = ct * 8 + w;                 // col-tile of 16 within [0,16)
            bf16x8 b = *(const bf16x8*)(f1wb + ((size_t)(s * 16 + fc) * 64 + l) * 8);
            #pragma unroll
            for (int rt = 0; rt < 4; ++rt) acc1[rt] = MFMA16(a[rt], b, acc1[rt]);
        }
        {
            int colh = w * 16 + r16;
            float fb = F1b[ct * 128 + colh];
            #pragma unroll
            for (int rt = 0; rt < 4; ++rt)
                #pragma unroll
                for (int j = 0; j < 4; ++j)
                    u_lds[swz(rt * 16 + g16 * 4 + j, colh)] =
                        f2bf(fmaxf(acc1[rt][j] + fb, 0.f));
        }
        __syncthreads();
        // FFN2 partial over this K-half; wave w computes cols [w*16, w*16+16)
        #pragma unroll
        for (int ks = 0; ks < 4; ++ks) {
            bf16x8 a2[4];
            #pragma unroll
            for (int rt = 0; rt < 4; ++rt)
                a2[rt] = *(const bf16x8*)&u_lds[swz(rt * 16 + r16, ks * 32 + g16 * 8)];
            int sg = ct * 4 + ks;
            bf16x8 b = *(const bf16x8*)(f2wb + ((size_t)(sg * 8 + w) * 64 + l) * 8);
            #pragma unroll
            for (int rt = 0; rt < 4; ++rt) acc2[rt] = MFMA16(a2[rt], b, acc2[rt]);
        }
        __syncthreads();  // protect u_lds WAR before next half
    }

    // epilogue: z = x + acc2 + F2b (bf16 to global); bn2 column sums
    {
        int col = w * 16 + r16;
        float fb = F2b[col];
        float cs = 0.f, cq = 0.f;
        #pragma unroll
        for (int rt = 0; rt < 4; ++rt)
            #pragma unroll
            for (int j = 0; j < 4; ++j) {
                int lr = rt * 16 + g16 * 4 + j;
                float xv = bf2f(x_lds[swz(lr, col)]);
                float zv = xv + acc2[rt][j] + fb;
                zb[(size_t)(rowb + lr) * DD + col] = f2bf(zv);
                cs += zv; cq += zv * zv;
            }
        cs += __shfl_xor(cs, 16); cs += __shfl_xor(cs, 32);
        cq += __shfl_xor(cq, 16); cq += __shfl_xor(cq, 32);
        if (g16 == 0) {
            atomicAdd(&bnsum2[col], cs);
            atomicAdd(&bnsq2[col], cq);
        }
    }
}

// ---------------------------------------------------------------------------
// K5: out = bn2(z) — bf16x8 read, float4 x2 write per thread.
// ---------------------------------------------------------------------------
__global__ __launch_bounds__(256) void k_out(const unsigned short* __restrict__ zb,
                                             const float* __restrict__ bnsum,
                                             const float* __restrict__ bnsq,
                                             const float* __restrict__ gam,
                                             const float* __restrict__ bet,
                                             float* __restrict__ out) {
    int idx = blockIdx.x * 256 + threadIdx.x;  // over N*16 bf16x8 chunks
    int base = idx * 8;
    int c0 = base & 127;
    const float inv = 1.f / NN;
    bf16x8 zv = *(const bf16x8*)(zb + base);
    float o[8];
    #pragma unroll
    for (int j = 0; j < 8; ++j) {
        int c = c0 + j;
        float mu = bnsum[c] * inv;
        float var = bnsq[c] * inv - mu * mu;
        float sc = gam[c] * rsqrtf(var + EPSV);
        float sh = bet[c] - mu * sc;
        o[j] = bf2f((unsigned short)zv[j]) * sc + sh;
    }
    float4 o0 = {o[0], o[1], o[2], o[3]};
    float4 o1 = {o[4], o[5], o[6], o[7]};
    *(float4*)(out + base) = o0;
    *(float4*)(out + base + 4) = o1;
}

// ---------------------------------------------------------------------------
extern "C" void kernel_launch(void* const* d_in, const int* in_sizes, int n_in,
                              void* d_out, int out_size, void* d_ws, size_t ws_size,
                              hipStream_t stream) {
    const float* h    = (const float*)d_in[0];
    const int*   nbr  = (const int*)d_in[1];
    const float* W1   = (const float*)d_in[2];
    const float* b1   = (const float*)d_in[3];
    const float* W2   = (const float*)d_in[4];
    const float* b2   = (const float*)d_in[5];
    const float* OW   = (const float*)d_in[6];
    const float* Ob   = (const float*)d_in[7];
    const float* bn1g = (const float*)d_in[8];
    const float* bn1b = (const float*)d_in[9];
    const float* F1W  = (const float*)d_in[10];
    const float* F1b  = (const float*)d_in[11];
    const float* F2W  = (const float*)d_in[12];
    const float* F2b  = (const float*)d_in[13];
    const float* bn2g = (const float*)d_in[14];
    const float* bn2b = (const float*)d_in[15];
    float* out = (float*)d_out;

    char* wsb = (char*)d_ws;
    unsigned short* gb = (unsigned short*)wsb;                        // 8 MB bf16
    unsigned short* tb = (unsigned short*)(wsb + ((size_t)8 << 20));  // 8 MB bf16
    unsigned short* zb = (unsigned short*)(wsb + ((size_t)16 << 20)); // 8 MB bf16
    char* wtb = wsb + ((size_t)24 << 20);
    short* w1b  = (short*)wtb;                                        // 32 KB
    short* owb  = w1b + 16384;                                        // 64 KB
    short* f1wb = owb + 32768;                                        // 64 KB
    short* f2wb = f1wb + 32768;                                       // 64 KB
    float* stats = (float*)(f2wb + 32768);
    float* bnsum1 = stats;
    float* bnsq1  = stats + 128;
    float* bnsum2 = stats + 256;
    float* bnsq2  = stats + 384;
    float* amean  = stats + 512;           // N floats
    float* amaxv  = amean + NN;            // N floats
    float* aminv  = amaxv + NN;            // N floats

    k_prep_w4<<<58, 256, 0, stream>>>(W1, OW, F1W, F2W, w1b, owb, f1wb, f2wb, stats);
    k_g<<<NN / 64, 256, 0, stream>>>(h, w1b, gb);
    k_att<<<NN / 4, 256, 0, stream>>>(gb, nbr, b1, W2, b2, amean, amaxv, aminv);
    k_t<<<NN / 64, 256, 0, stream>>>((const short*)owb, h, Ob, amean, amaxv, aminv,
                                     tb, bnsum1, bnsq1);
    k_ffn12<<<NN / 64, 512, 0, stream>>>(tb, (const short*)f1wb, F1b,
                                         (const short*)f2wb, F2b, bn1g, bn1b,
                                         bnsum1, bnsq1, zb, bnsum2, bnsq2);
    k_out<<<NN * 16 / 256, 256, 0, stream>>>(zb, bnsum2, bnsq2, bn2g, bn2b, out);
}

// Round 13
// 79.673 us; speedup vs baseline: 2.0683x; 1.1153x over previous
//
#include <hip/hip_runtime.h>
#include <math.h>

#define NN 32768
#define KK 16
#define DD 128
#define EPSV 1e-5f

typedef __attribute__((ext_vector_type(8))) short bf16x8;
typedef __attribute__((ext_vector_type(4))) float f32x4;

__device__ __forceinline__ unsigned short f2bf(float x) {
    unsigned u; __builtin_memcpy(&u, &x, 4);
    u += 0x7fffu + ((u >> 16) & 1u);          // RNE (finite inputs)
    return (unsigned short)(u >> 16);
}
__device__ __forceinline__ float bf2f(unsigned short b) {
    unsigned u = ((unsigned)b) << 16; float f; __builtin_memcpy(&f, &u, 4); return f;
}

#define MFMA16(a, b, c) __builtin_amdgcn_mfma_f32_16x16x32_bf16((a), (b), (c), 0, 0, 0)

// LDS index swizzle for [64][128] bf16 tiles: flip ushort-index bits 3..5
// with row&7 so strided row reads spread across banks.
__device__ __forceinline__ int swz(int row, int col) {
    return row * 128 + (col ^ ((row & 7) << 3));
}

// ---------------------------------------------------------------------------
// Weight prep: 4 weight matrices -> bf16 B-fragment order; also zero stats.
// Frag (s,c,lane l): elems j=0..7 = B[32s + 8*(l>>4) + j][16c + (l&15)],
// stored at out[((s*NT + c)*64 + l)*8 + j].
// ---------------------------------------------------------------------------
__global__ __launch_bounds__(256) void k_prep_w4(const float* __restrict__ W1,
                                                 const float* __restrict__ OW,
                                                 const float* __restrict__ F1W,
                                                 const float* __restrict__ F2W,
                                                 short* __restrict__ w1b,
                                                 short* __restrict__ owb,
                                                 short* __restrict__ f1wb,
                                                 short* __restrict__ f2wb,
                                                 float* __restrict__ stats) {
    int tid = blockIdx.x * 256 + threadIdx.x;
    if (tid >= 14848) return;
    if (tid >= 14336) { stats[tid - 14336] = 0.f; return; }
    const float* W; short* out; int Ncol; int base;
    if (tid < 2048)       { W = W1;  out = w1b;  Ncol = 128; base = 0; }
    else if (tid < 6144)  { W = OW;  out = owb;  Ncol = 128; base = 2048; }
    else if (tid < 10240) { W = F1W; out = f1wb; Ncol = 256; base = 6144; }
    else                  { W = F2W; out = f2wb; Ncol = 128; base = 10240; }
    int t = tid - base;
    int l = t & 63, sc = t >> 6;
    int NT = Ncol >> 4;
    int c = sc % NT, s = sc / NT;
    int col = c * 16 + (l & 15);
    int k0 = s * 32 + (l >> 4) * 8;
    bf16x8 v;
    #pragma unroll
    for (int j = 0; j < 8; ++j) v[j] = (short)f2bf(W[(size_t)(k0 + j) * Ncol + col]);
    *(bf16x8*)(out + (size_t)t * 8) = v;
}

// ---------------------------------------------------------------------------
// K1: gb = bf16(h @ W1). 512 blocks x 8 waves (512 thr), 64 rows/block.
// phase1: bf16(h) -> LDS once; GEMM: wave = 64 rows x 16 cols, A from LDS.
// ---------------------------------------------------------------------------
__global__ __launch_bounds__(512) void k_g(const float* __restrict__ h,
                                           const short* __restrict__ w1b,
                                           unsigned short* __restrict__ gb) {
    __shared__ unsigned short h_lds[64 * 128];   // 16 KB
    const int t = threadIdx.x, w = t >> 6, l = t & 63;
    const int g16 = l >> 4, r16 = l & 15;
    const int rowb = blockIdx.x * 64;

    // stage bf16(h) tile
    {
        int row = t >> 3, c0 = (t & 7) * 16;
        #pragma unroll
        for (int i = 0; i < 2; ++i) {
            int c = c0 + i * 8;
            const float* hp = h + (size_t)(rowb + row) * DD + c;
            float4 x0 = *(const float4*)hp;
            float4 x1 = *(const float4*)(hp + 4);
            bf16x8 hv;
            hv[0] = (short)f2bf(x0.x); hv[1] = (short)f2bf(x0.y);
            hv[2] = (short)f2bf(x0.z); hv[3] = (short)f2bf(x0.w);
            hv[4] = (short)f2bf(x1.x); hv[5] = (short)f2bf(x1.y);
            hv[6] = (short)f2bf(x1.z); hv[7] = (short)f2bf(x1.w);
            *(bf16x8*)&h_lds[swz(row, c)] = hv;
        }
    }
    __syncthreads();

    f32x4 acc[4];
    #pragma unroll
    for (int rt = 0; rt < 4; ++rt) acc[rt] = (f32x4){0.f, 0.f, 0.f, 0.f};
    #pragma unroll
    for (int s = 0; s < 4; ++s) {
        bf16x8 a[4];
        #pragma unroll
        for (int rt = 0; rt < 4; ++rt)
            a[rt] = *(const bf16x8*)&h_lds[swz(rt * 16 + r16, s * 32 + g16 * 8)];
        bf16x8 b = *(const bf16x8*)(w1b + ((size_t)(s * 8 + w) * 64 + l) * 8);
        #pragma unroll
        for (int rt = 0; rt < 4; ++rt) acc[rt] = MFMA16(a[rt], b, acc[rt]);
    }
    int col = w * 16 + r16;
    #pragma unroll
    for (int rt = 0; rt < 4; ++rt)
        #pragma unroll
        for (int j = 0; j < 4; ++j)
            gb[(size_t)(rowb + rt * 16 + g16 * 4 + j) * DD + col] = f2bf(acc[rt][j]);
}

// ---------------------------------------------------------------------------
// K2: per-node attention stats. One wave per node, 16-lane groups.
// ---------------------------------------------------------------------------
__global__ __launch_bounds__(256) void k_att(const unsigned short* __restrict__ gb,
                                             const int* __restrict__ nbr,
                                             const float* __restrict__ b1,
                                             const float* __restrict__ W2,
                                             const float* __restrict__ b2,
                                             float* __restrict__ amean,
                                             float* __restrict__ amaxv,
                                             float* __restrict__ aminv) {
    const int t = threadIdx.x;
    const int w = t >> 6, lane = t & 63;
    const int node = blockIdx.x * 4 + w;
    const int grp = lane >> 4, r = lane & 15;

    bf16x8 gd8 = *(const bf16x8*)((const short*)gb + (size_t)node * DD + r * 8);
    float gd[8];
    #pragma unroll
    for (int j = 0; j < 8; ++j) gd[j] = bf2f((unsigned short)gd8[j]);
    float4 b1a = *(const float4*)(b1 + r * 8);
    float4 b1b = *(const float4*)(b1 + r * 8 + 4);
    float4 w2a = *(const float4*)(W2 + r * 8);
    float4 w2b = *(const float4*)(W2 + r * 8 + 4);
    const float b1v[8] = {b1a.x, b1a.y, b1a.z, b1a.w, b1b.x, b1b.y, b1b.z, b1b.w};
    const float w2v[8] = {w2a.x, w2a.y, w2a.z, w2a.w, w2b.x, w2b.y, w2b.z, w2b.w};
    const float b2s = b2[0];

    int4 nb4 = *(const int4*)(nbr + node * KK + grp * 4);
    const int srcs[4] = {nb4.x, nb4.y, nb4.z, nb4.w};

    float asum = 0.f, amx = -1e30f, amn = 1e30f;
    #pragma unroll
    for (int it = 0; it < 4; ++it) {
        bf16x8 gs8 = *(const bf16x8*)((const short*)gb + (size_t)srcs[it] * DD + r * 8);
        float v = 0.f;
        #pragma unroll
        for (int j = 0; j < 8; ++j)
            v += fmaxf(bf2f((unsigned short)gs8[j]) - gd[j] + b1v[j], 0.f) * w2v[j];
        v += __shfl_xor(v, 1); v += __shfl_xor(v, 2);
        v += __shfl_xor(v, 4); v += __shfl_xor(v, 8);
        float s = fmaxf(v + b2s, 0.f);
        float att = __expf(-s);
        asum += att;
        amx = fmaxf(amx, att);
        amn = fminf(amn, att);
    }
    asum += __shfl_xor(asum, 16); asum += __shfl_xor(asum, 32);
    amx = fmaxf(amx, __shfl_xor(amx, 16)); amx = fmaxf(amx, __shfl_xor(amx, 32));
    amn = fminf(amn, __shfl_xor(amn, 16)); amn = fminf(amn, __shfl_xor(amn, 32));
    if (lane == 0) {
        amean[node] = asum * (1.f / KK);
        amaxv[node] = amx;
        aminv[node] = amn;
    }
}

// ---------------------------------------------------------------------------
// K3: t = h + [am*h || sel*h] @ OW + Ob; 512 blocks x 8 waves (512 thr).
// phase1: aM/aS tiles -> LDS once; GEMM: wave = 64 rows x 16 cols, A from LDS.
// t stored BF16; fused bn1 column sums.
// ---------------------------------------------------------------------------
__global__ __launch_bounds__(512) void k_t(const short* __restrict__ owb,
                                           const float* __restrict__ h,
                                           const float* __restrict__ Ob,
                                           const float* __restrict__ amean,
                                           const float* __restrict__ amaxv,
                                           const float* __restrict__ aminv,
                                           unsigned short* __restrict__ tb,
                                           float* __restrict__ bnsum,
                                           float* __restrict__ bnsq) {
    __shared__ unsigned short aM_lds[64 * 128];  // 16 KB
    __shared__ unsigned short aS_lds[64 * 128];  // 16 KB
    const int t = threadIdx.x, w = t >> 6, l = t & 63;
    const int g16 = l >> 4, r16 = l & 15;
    const int rowb = blockIdx.x * 64;

    // stage aM = bf16(am*h), aS = bf16(sel*h) tiles
    {
        int row = t >> 3, c0 = (t & 7) * 16;
        float am = amean[rowb + row], ax = amaxv[rowb + row], an = aminv[rowb + row];
        #pragma unroll
        for (int i = 0; i < 2; ++i) {
            int c = c0 + i * 8;
            const float* hp = h + (size_t)(rowb + row) * DD + c;
            float4 x0 = *(const float4*)hp;
            float4 x1 = *(const float4*)(hp + 4);
            float v[8] = {x0.x, x0.y, x0.z, x0.w, x1.x, x1.y, x1.z, x1.w};
            bf16x8 m, sfr;
            #pragma unroll
            for (int j = 0; j < 8; ++j) {
                m[j]   = (short)f2bf(am * v[j]);
                sfr[j] = (short)f2bf((v[j] >= 0.f ? ax : an) * v[j]);
            }
            *(bf16x8*)&aM_lds[swz(row, c)] = m;
            *(bf16x8*)&aS_lds[swz(row, c)] = sfr;
        }
    }
    __syncthreads();

    f32x4 acc[4];
    #pragma unroll
    for (int rt = 0; rt < 4; ++rt) acc[rt] = (f32x4){0.f, 0.f, 0.f, 0.f};
    #pragma unroll
    for (int s = 0; s < 4; ++s) {
        bf16x8 aM[4], aS[4];
        #pragma unroll
        for (int rt = 0; rt < 4; ++rt) {
            aM[rt] = *(const bf16x8*)&aM_lds[swz(rt * 16 + r16, s * 32 + g16 * 8)];
            aS[rt] = *(const bf16x8*)&aS_lds[swz(rt * 16 + r16, s * 32 + g16 * 8)];
        }
        bf16x8 bM = *(const bf16x8*)(owb + ((size_t)(s * 8 + w) * 64 + l) * 8);
        bf16x8 bS = *(const bf16x8*)(owb + ((size_t)((s + 4) * 8 + w) * 64 + l) * 8);
        #pragma unroll
        for (int rt = 0; rt < 4; ++rt) {
            acc[rt] = MFMA16(aM[rt], bM, acc[rt]);
            acc[rt] = MFMA16(aS[rt], bS, acc[rt]);
        }
    }

    // epilogue: t = h + acc + Ob; bn1 sums (wave owns its 16 cols)
    {
        int col = w * 16 + r16;
        float ob = Ob[col];
        float cs = 0.f, cq = 0.f;
        #pragma unroll
        for (int rt = 0; rt < 4; ++rt)
            #pragma unroll
            for (int j = 0; j < 4; ++j) {
                int row = rowb + rt * 16 + g16 * 4 + j;
                size_t idx = (size_t)row * DD + col;
                float tv = h[idx] + acc[rt][j] + ob;
                tb[idx] = f2bf(tv);
                cs += tv; cq += tv * tv;
            }
        cs += __shfl_xor(cs, 16); cs += __shfl_xor(cs, 32);
        cq += __shfl_xor(cq, 16); cq += __shfl_xor(cq, 32);
        if (g16 == 0) {
            atomicAdd(&bnsum[col], cs);
            atomicAdd(&bnsq[col], cq);
        }
    }
}

// ---------------------------------------------------------------------------
// K4: fused FFN1+FFN2. 512 blocks x 8 waves (512 thr), 64 rows/block.
//   phase0: sc/sh(bn1) table -> LDS
//   phase1: x = bn1(t) bf16 -> x_lds (swizzled)
//   per column-half: FFN1 (wave = 64x16) -> u half in LDS
//                    -> acc2 += u @ F2W-half (wave = 64x16)
//   epilogue: z = x + acc2 + F2b -> global (bf16); bn2 sums via shfl+atomics.
// ---------------------------------------------------------------------------
__global__ __launch_bounds__(512) void k_ffn12(const unsigned short* __restrict__ tb,
                                               const short* __restrict__ f1wb,
                                               const float* __restrict__ F1b,
                                               const short* __restrict__ f2wb,
                                               const float* __restrict__ F2b,
                                               const float* __restrict__ bn1g,
                                               const float* __restrict__ bn1b,
                                               const float* __restrict__ bnsum1,
                                               const float* __restrict__ bnsq1,
                                               unsigned short* __restrict__ zb,
                                               float* __restrict__ bnsum2,
                                               float* __restrict__ bnsq2) {
    __shared__ unsigned short x_lds[64 * 128];   // 16 KB  (x = bn1(t), bf16)
    __shared__ unsigned short u_lds[64 * 128];   // 16 KB  (one column-half of u)
    __shared__ float sc_l[128], sh_l[128];

    const int t = threadIdx.x, w = t >> 6, l = t & 63;
    const int g16 = l >> 4, r16 = l & 15;
    const int rowb = blockIdx.x * 64;
    const float inv = 1.f / NN;

    // phase0: bn1 scale/shift per column
    if (t < 128) {
        float mu = bnsum1[t] * inv;
        float var = bnsq1[t] * inv - mu * mu;
        float sc = bn1g[t] * rsqrtf(var + EPSV);
        sc_l[t] = sc;
        sh_l[t] = bn1b[t] - mu * sc;
    }
    __syncthreads();

    // phase1: stage x = bn1(t) into LDS (each thread: 1 row, 16 cols)
    {
        int row = t >> 3, c0 = (t & 7) * 16;
        #pragma unroll
        for (int i = 0; i < 2; ++i) {
            int c = c0 + i * 8;
            bf16x8 v = *(const bf16x8*)(tb + (size_t)(rowb + row) * DD + c);
            bf16x8 xv;
            #pragma unroll
            for (int j = 0; j < 8; ++j)
                xv[j] = (short)f2bf(bf2f((unsigned short)v[j]) * sc_l[c + j] + sh_l[c + j]);
            *(bf16x8*)&x_lds[swz(row, c)] = xv;
        }
    }
    __syncthreads();

    f32x4 acc2[4];
    #pragma unroll
    for (int rt = 0; rt < 4; ++rt) acc2[rt] = (f32x4){0.f, 0.f, 0.f, 0.f};

    #pragma unroll 1
    for (int ct = 0; ct < 2; ++ct) {
        // FFN1: u_half(64x128); wave w computes 64 rows x cols [w*16, w*16+16)
        f32x4 acc1[4];
        #pragma unroll
        for (int rt = 0; rt < 4; ++rt) acc1[rt] = (f32x4){0.f, 0.f, 0.f, 0.f};
        #pragma unroll
        for (int s = 0; s < 4; ++s) {
            bf16x8 a[4];
            #pragma unroll
            for (int rt = 0; rt < 4; ++rt)
                a[rt] = *(const bf16x8*)&x_lds[swz(rt * 16 + r16, s * 32 + g16 * 8)];
            int fc = ct * 8 + w;                 // col-tile of 16 within [0,16)
            bf16x8 b = *(const bf16x8*)(f1wb + ((size_t)(s * 16 + fc) * 64 + l) * 8);
            #pragma unroll
            for (int rt = 0; rt < 4; ++rt) acc1[rt] = MFMA16(a[rt], b, acc1[rt]);
        }
        {
            int colh = w * 16 + r16;
            float fb = F1b[ct * 128 + colh];
            #pragma unroll
            for (int rt = 0; rt < 4; ++rt)
                #pragma unroll
                for (int j = 0; j < 4; ++j)
                    u_lds[swz(rt * 16 + g16 * 4 + j, colh)] =
                        f2bf(fmaxf(acc1[rt][j] + fb, 0.f));
        }
        __syncthreads();
        // FFN2 partial over this K-half; wave w computes cols [w*16, w*16+16)
        #pragma unroll
        for (int ks = 0; ks < 4; ++ks) {
            bf16x8 a2[4];
            #pragma unroll
            for (int rt = 0; rt < 4; ++rt)
                a2[rt] = *(const bf16x8*)&u_lds[swz(rt * 16 + r16, ks * 32 + g16 * 8)];
            int sg = ct * 4 + ks;
            bf16x8 b = *(const bf16x8*)(f2wb + ((size_t)(sg * 8 + w) * 64 + l) * 8);
            #pragma unroll
            for (int rt = 0; rt < 4; ++rt) acc2[rt] = MFMA16(a2[rt], b, acc2[rt]);
        }
        __syncthreads();  // protect u_lds WAR before next half
    }

    // epilogue: z = x + acc2 + F2b (bf16 to global); bn2 column sums
    {
        int col = w * 16 + r16;
        float fb = F2b[col];
        float cs = 0.f, cq = 0.f;
        #pragma unroll
        for (int rt = 0; rt < 4; ++rt)
            #pragma unroll
            for (int j = 0; j < 4; ++j) {
                int lr = rt * 16 + g16 * 4 + j;
                float xv = bf2f(x_lds[swz(lr, col)]);
                float zv = xv + acc2[rt][j] + fb;
                zb[(size_t)(rowb + lr) * DD + col] = f2bf(zv);
                cs += zv; cq += zv * zv;
            }
        cs += __shfl_xor(cs, 16); cs += __shfl_xor(cs, 32);
        cq += __shfl_xor(cq, 16); cq += __shfl_xor(cq, 32);
        if (g16 == 0) {
            atomicAdd(&bnsum2[col], cs);
            atomicAdd(&bnsq2[col], cq);
        }
    }
}

// ---------------------------------------------------------------------------
// K5: out = bn2(z) — bf16x8 read, float4 x2 write per thread.
// ---------------------------------------------------------------------------
__global__ __launch_bounds__(256) void k_out(const unsigned short* __restrict__ zb,
                                             const float* __restrict__ bnsum,
                                             const float* __restrict__ bnsq,
                                             const float* __restrict__ gam,
                                             const float* __restrict__ bet,
                                             float* __restrict__ out) {
    int idx = blockIdx.x * 256 + threadIdx.x;  // over N*16 bf16x8 chunks
    int base = idx * 8;
    int c0 = base & 127;
    const float inv = 1.f / NN;
    bf16x8 zv = *(const bf16x8*)(zb + base);
    float o[8];
    #pragma unroll
    for (int j = 0; j < 8; ++j) {
        int c = c0 + j;
        float mu = bnsum[c] * inv;
        float var = bnsq[c] * inv - mu * mu;
        float sc = gam[c] * rsqrtf(var + EPSV);
        float sh = bet[c] - mu * sc;
        o[j] = bf2f((unsigned short)zv[j]) * sc + sh;
    }
    float4 o0 = {o[0], o[1], o[2], o[3]};
    float4 o1 = {o[4], o[5], o[6], o[7]};
    *(float4*)(out + base) = o0;
    *(float4*)(out + base + 4) = o1;
}

// ---------------------------------------------------------------------------
extern "C" void kernel_launch(void* const* d_in, const int* in_sizes, int n_in,
                              void* d_out, int out_size, void* d_ws, size_t ws_size,
                              hipStream_t stream) {
    const float* h    = (const float*)d_in[0];
    const int*   nbr  = (const int*)d_in[1];
    const float* W1   = (const float*)d_in[2];
    const float* b1   = (const float*)d_in[3];
    const float* W2   = (const float*)d_in[4];
    const float* b2   = (const float*)d_in[5];
    const float* OW   = (const float*)d_in[6];
    const float* Ob   = (const float*)d_in[7];
    const float* bn1g = (const float*)d_in[8];
    const float* bn1b = (const float*)d_in[9];
    const float* F1W  = (const float*)d_in[10];
    const float* F1b  = (const float*)d_in[11];
    const float* F2W  = (const float*)d_in[12];
    const float* F2b  = (const float*)d_in[13];
    const float* bn2g = (const float*)d_in[14];
    const float* bn2b = (const float*)d_in[15];
    float* out = (float*)d_out;

    char* wsb = (char*)d_ws;
    unsigned short* gb = (unsigned short*)wsb;                        // 8 MB bf16
    unsigned short* tb = (unsigned short*)(wsb + ((size_t)8 << 20));  // 8 MB bf16
    unsigned short* zb = (unsigned short*)(wsb + ((size_t)16 << 20)); // 8 MB bf16
    char* wtb = wsb + ((size_t)24 << 20);
    short* w1b  = (short*)wtb;                                        // 32 KB
    short* owb  = w1b + 16384;                                        // 64 KB
    short* f1wb = owb + 32768;                                        // 64 KB
    short* f2wb = f1wb + 32768;                                       // 64 KB
    float* stats = (float*)(f2wb + 32768);
    float* bnsum1 = stats;
    float* bnsq1  = stats + 128;
    float* bnsum2 = stats + 256;
    float* bnsq2  = stats + 384;
    float* amean  = stats + 512;           // N floats
    float* amaxv  = amean + NN;            // N floats
    float* aminv  = amaxv + NN;            // N floats

    k_prep_w4<<<58, 256, 0, stream>>>(W1, OW, F1W, F2W, w1b, owb, f1wb, f2wb, stats);
    k_g<<<NN / 64, 512, 0, stream>>>(h, w1b, gb);
    k_att<<<NN / 4, 256, 0, stream>>>(gb, nbr, b1, W2, b2, amean, amaxv, aminv);
    k_t<<<NN / 64, 512, 0, stream>>>((const short*)owb, h, Ob, amean, amaxv, aminv,
                                     tb, bnsum1, bnsq1);
    k_ffn12<<<NN / 64, 512, 0, stream>>>(tb, (const short*)f1wb, F1b,
                                         (const short*)f2wb, F2b, bn1g, bn1b,
                                         bnsum1, bnsq1, zb, bnsum2, bnsq2);
    k_out<<<NN * 16 / 256, 256, 0, stream>>>(zb, bnsum2, bnsq2, bn2g, bn2b, out);
}

// Round 14
// 78.605 us; speedup vs baseline: 2.0964x; 1.0136x over previous
//
#include <hip/hip_runtime.h>
#include <math.h>

#define NN 32768
#define KK 16
#define DD 128
#define EPSV 1e-5f

typedef __attribute__((ext_vector_type(8))) short bf16x8;
typedef __attribute__((ext_vector_type(4))) float f32x4;

__device__ __forceinline__ unsigned short f2bf(float x) {
    unsigned u; __builtin_memcpy(&u, &x, 4);
    u += 0x7fffu + ((u >> 16) & 1u);          // RNE (finite inputs)
    return (unsigned short)(u >> 16);
}
__device__ __forceinline__ float bf2f(unsigned short b) {
    unsigned u = ((unsigned)b) << 16; float f; __builtin_memcpy(&f, &u, 4); return f;
}

#define MFMA16(a, b, c) __builtin_amdgcn_mfma_f32_16x16x32_bf16((a), (b), (c), 0, 0, 0)

// LDS index swizzle for [64][128] bf16 tiles.
__device__ __forceinline__ int swz(int row, int col) {
    return row * 128 + (col ^ ((row & 7) << 3));
}
// Same swizzle for [64][256] bf16 tiles.
__device__ __forceinline__ int swz256(int row, int col) {
    return row * 256 + (col ^ ((row & 7) << 3));
}

// ---------------------------------------------------------------------------
// K0: small prep — W1 -> bf16 B-fragment order + zero stats.
// Frag (s,c,lane l): elems j=0..7 = B[32s + 8*(l>>4) + j][16c + (l&15)].
// ---------------------------------------------------------------------------
__global__ __launch_bounds__(256) void k_prep(const float* __restrict__ W1,
                                              short* __restrict__ w1b,
                                              float* __restrict__ stats) {
    int tid = blockIdx.x * 256 + threadIdx.x;
    if (tid >= 2560) return;
    if (tid >= 2048) { stats[tid - 2048] = 0.f; return; }
    int l = tid & 63, sc = tid >> 6;
    int c = sc & 7, s = sc >> 3;
    int col = c * 16 + (l & 15);
    int k0 = s * 32 + (l >> 4) * 8;
    bf16x8 v;
    #pragma unroll
    for (int j = 0; j < 8; ++j) v[j] = (short)f2bf(W1[(size_t)(k0 + j) * DD + col]);
    *(bf16x8*)(w1b + (size_t)tid * 8) = v;
}

// ---------------------------------------------------------------------------
// K1: gb = bf16(h @ W1). Blocks 0..511: GEMM (8 waves, 64 rows, A from LDS).
// Blocks 512..535: prep OW/F1W/F2W -> bf16 fragment tables (needed later
// by k_t / k_ffn12, NOT by k_g itself — overlaps the GEMM).
// ---------------------------------------------------------------------------
__global__ __launch_bounds__(512) void k_g(const float* __restrict__ h,
                                           const short* __restrict__ w1b,
                                           unsigned short* __restrict__ gb,
                                           const float* __restrict__ OW,
                                           const float* __restrict__ F1W,
                                           const float* __restrict__ F2W,
                                           short* __restrict__ owb,
                                           short* __restrict__ f1wb,
                                           short* __restrict__ f2wb) {
    if (blockIdx.x >= NN / 64) {
        // ---- weight-prep tail: 24 blocks x 512 thr = 12288 fragment-threads
        int tid = (blockIdx.x - NN / 64) * 512 + threadIdx.x;
        const float* W; short* out; int Ncol;
        if (tid < 4096)      { W = OW;  out = owb;  Ncol = 128; }
        else if (tid < 8192) { W = F1W; out = f1wb; Ncol = 256; tid -= 4096; }
        else                 { W = F2W; out = f2wb; Ncol = 128; tid -= 8192; }
        int l = tid & 63, sc = tid >> 6;
        int NT = Ncol >> 4;
        int c = sc % NT, s = sc / NT;
        int col = c * 16 + (l & 15);
        int k0 = s * 32 + (l >> 4) * 8;
        bf16x8 v;
        #pragma unroll
        for (int j = 0; j < 8; ++j) v[j] = (short)f2bf(W[(size_t)(k0 + j) * Ncol + col]);
        *(bf16x8*)(out + (size_t)tid * 8) = v;
        return;
    }

    __shared__ unsigned short h_lds[64 * 128];   // 16 KB
    const int t = threadIdx.x, w = t >> 6, l = t & 63;
    const int g16 = l >> 4, r16 = l & 15;
    const int rowb = blockIdx.x * 64;

    // stage bf16(h) tile
    {
        int row = t >> 3, c0 = (t & 7) * 16;
        #pragma unroll
        for (int i = 0; i < 2; ++i) {
            int c = c0 + i * 8;
            const float* hp = h + (size_t)(rowb + row) * DD + c;
            float4 x0 = *(const float4*)hp;
            float4 x1 = *(const float4*)(hp + 4);
            bf16x8 hv;
            hv[0] = (short)f2bf(x0.x); hv[1] = (short)f2bf(x0.y);
            hv[2] = (short)f2bf(x0.z); hv[3] = (short)f2bf(x0.w);
            hv[4] = (short)f2bf(x1.x); hv[5] = (short)f2bf(x1.y);
            hv[6] = (short)f2bf(x1.z); hv[7] = (short)f2bf(x1.w);
            *(bf16x8*)&h_lds[swz(row, c)] = hv;
        }
    }
    __syncthreads();

    f32x4 acc[4];
    #pragma unroll
    for (int rt = 0; rt < 4; ++rt) acc[rt] = (f32x4){0.f, 0.f, 0.f, 0.f};
    #pragma unroll
    for (int s = 0; s < 4; ++s) {
        bf16x8 a[4];
        #pragma unroll
        for (int rt = 0; rt < 4; ++rt)
            a[rt] = *(const bf16x8*)&h_lds[swz(rt * 16 + r16, s * 32 + g16 * 8)];
        bf16x8 b = *(const bf16x8*)(w1b + ((size_t)(s * 8 + w) * 64 + l) * 8);
        #pragma unroll
        for (int rt = 0; rt < 4; ++rt) acc[rt] = MFMA16(a[rt], b, acc[rt]);
    }
    int col = w * 16 + r16;
    #pragma unroll
    for (int rt = 0; rt < 4; ++rt)
        #pragma unroll
        for (int j = 0; j < 4; ++j)
            gb[(size_t)(rowb + rt * 16 + g16 * 4 + j) * DD + col] = f2bf(acc[rt][j]);
}

// ---------------------------------------------------------------------------
// K2: per-node attention stats. One wave per node, 16-lane groups.
// ---------------------------------------------------------------------------
__global__ __launch_bounds__(256) void k_att(const unsigned short* __restrict__ gb,
                                             const int* __restrict__ nbr,
                                             const float* __restrict__ b1,
                                             const float* __restrict__ W2,
                                             const float* __restrict__ b2,
                                             float* __restrict__ amean,
                                             float* __restrict__ amaxv,
                                             float* __restrict__ aminv) {
    const int t = threadIdx.x;
    const int w = t >> 6, lane = t & 63;
    const int node = blockIdx.x * 4 + w;
    const int grp = lane >> 4, r = lane & 15;

    bf16x8 gd8 = *(const bf16x8*)((const short*)gb + (size_t)node * DD + r * 8);
    float gd[8];
    #pragma unroll
    for (int j = 0; j < 8; ++j) gd[j] = bf2f((unsigned short)gd8[j]);
    float4 b1a = *(const float4*)(b1 + r * 8);
    float4 b1b = *(const float4*)(b1 + r * 8 + 4);
    float4 w2a = *(const float4*)(W2 + r * 8);
    float4 w2b = *(const float4*)(W2 + r * 8 + 4);
    const float b1v[8] = {b1a.x, b1a.y, b1a.z, b1a.w, b1b.x, b1b.y, b1b.z, b1b.w};
    const float w2v[8] = {w2a.x, w2a.y, w2a.z, w2a.w, w2b.x, w2b.y, w2b.z, w2b.w};
    const float b2s = b2[0];

    int4 nb4 = *(const int4*)(nbr + node * KK + grp * 4);
    const int srcs[4] = {nb4.x, nb4.y, nb4.z, nb4.w};

    float asum = 0.f, amx = -1e30f, amn = 1e30f;
    #pragma unroll
    for (int it = 0; it < 4; ++it) {
        bf16x8 gs8 = *(const bf16x8*)((const short*)gb + (size_t)srcs[it] * DD + r * 8);
        float v = 0.f;
        #pragma unroll
        for (int j = 0; j < 8; ++j)
            v += fmaxf(bf2f((unsigned short)gs8[j]) - gd[j] + b1v[j], 0.f) * w2v[j];
        v += __shfl_xor(v, 1); v += __shfl_xor(v, 2);
        v += __shfl_xor(v, 4); v += __shfl_xor(v, 8);
        float s = fmaxf(v + b2s, 0.f);
        float att = __expf(-s);
        asum += att;
        amx = fmaxf(amx, att);
        amn = fminf(amn, att);
    }
    asum += __shfl_xor(asum, 16); asum += __shfl_xor(asum, 32);
    amx = fmaxf(amx, __shfl_xor(amx, 16)); amx = fmaxf(amx, __shfl_xor(amx, 32));
    amn = fminf(amn, __shfl_xor(amn, 16)); amn = fminf(amn, __shfl_xor(amn, 32));
    if (lane == 0) {
        amean[node] = asum * (1.f / KK);
        amaxv[node] = amx;
        aminv[node] = amn;
    }
}

// ---------------------------------------------------------------------------
// K3: t = h + [am*h || sel*h] @ OW + Ob; 512 blocks x 8 waves (512 thr).
// phase1: aM/aS tiles -> LDS once; GEMM: wave = 64 rows x 16 cols, A from LDS.
// t stored BF16; fused bn1 column sums.
// ---------------------------------------------------------------------------
__global__ __launch_bounds__(512) void k_t(const short* __restrict__ owb,
                                           const float* __restrict__ h,
                                           const float* __restrict__ Ob,
                                           const float* __restrict__ amean,
                                           const float* __restrict__ amaxv,
                                           const float* __restrict__ aminv,
                                           unsigned short* __restrict__ tb,
                                           float* __restrict__ bnsum,
                                           float* __restrict__ bnsq) {
    __shared__ unsigned short aM_lds[64 * 128];  // 16 KB
    __shared__ unsigned short aS_lds[64 * 128];  // 16 KB
    const int t = threadIdx.x, w = t >> 6, l = t & 63;
    const int g16 = l >> 4, r16 = l & 15;
    const int rowb = blockIdx.x * 64;

    // stage aM = bf16(am*h), aS = bf16(sel*h) tiles
    {
        int row = t >> 3, c0 = (t & 7) * 16;
        float am = amean[rowb + row], ax = amaxv[rowb + row], an = aminv[rowb + row];
        #pragma unroll
        for (int i = 0; i < 2; ++i) {
            int c = c0 + i * 8;
            const float* hp = h + (size_t)(rowb + row) * DD + c;
            float4 x0 = *(const float4*)hp;
            float4 x1 = *(const float4*)(hp + 4);
            float v[8] = {x0.x, x0.y, x0.z, x0.w, x1.x, x1.y, x1.z, x1.w};
            bf16x8 m, sfr;
            #pragma unroll
            for (int j = 0; j < 8; ++j) {
                m[j]   = (short)f2bf(am * v[j]);
                sfr[j] = (short)f2bf((v[j] >= 0.f ? ax : an) * v[j]);
            }
            *(bf16x8*)&aM_lds[swz(row, c)] = m;
            *(bf16x8*)&aS_lds[swz(row, c)] = sfr;
        }
    }
    __syncthreads();

    f32x4 acc[4];
    #pragma unroll
    for (int rt = 0; rt < 4; ++rt) acc[rt] = (f32x4){0.f, 0.f, 0.f, 0.f};
    #pragma unroll
    for (int s = 0; s < 4; ++s) {
        bf16x8 aM[4], aS[4];
        #pragma unroll
        for (int rt = 0; rt < 4; ++rt) {
            aM[rt] = *(const bf16x8*)&aM_lds[swz(rt * 16 + r16, s * 32 + g16 * 8)];
            aS[rt] = *(const bf16x8*)&aS_lds[swz(rt * 16 + r16, s * 32 + g16 * 8)];
        }
        bf16x8 bM = *(const bf16x8*)(owb + ((size_t)(s * 8 + w) * 64 + l) * 8);
        bf16x8 bS = *(const bf16x8*)(owb + ((size_t)((s + 4) * 8 + w) * 64 + l) * 8);
        #pragma unroll
        for (int rt = 0; rt < 4; ++rt) {
            acc[rt] = MFMA16(aM[rt], bM, acc[rt]);
            acc[rt] = MFMA16(aS[rt], bS, acc[rt]);
        }
    }

    // epilogue: t = h + acc + Ob; bn1 sums (wave owns its 16 cols)
    {
        int col = w * 16 + r16;
        float ob = Ob[col];
        float cs = 0.f, cq = 0.f;
        #pragma unroll
        for (int rt = 0; rt < 4; ++rt)
            #pragma unroll
            for (int j = 0; j < 4; ++j) {
                int row = rowb + rt * 16 + g16 * 4 + j;
                size_t idx = (size_t)row * DD + col;
                float tv = h[idx] + acc[rt][j] + ob;
                tb[idx] = f2bf(tv);
                cs += tv; cq += tv * tv;
            }
        cs += __shfl_xor(cs, 16); cs += __shfl_xor(cs, 32);
        cq += __shfl_xor(cq, 16); cq += __shfl_xor(cq, 32);
        if (g16 == 0) {
            atomicAdd(&bnsum[col], cs);
            atomicAdd(&bnsq[col], cq);
        }
    }
}

// ---------------------------------------------------------------------------
// K4: fused FFN1+FFN2. 512 blocks x 8 waves (512 thr), 64 rows/block.
//   phase0: sc/sh(bn1) table -> LDS;  phase1: x = bn1(t) -> x_lds
//   FFN1 full-width: wave w -> col-tiles {w, w+8} -> full u (64x256) in LDS
//   one sync; FFN2 over K=256 -> acc2.
//   epilogue: z = x + acc2 + F2b -> global (bf16); bn2 sums via shfl+atomics.
// Accumulation order identical to prior version (bit-identical output).
// ---------------------------------------------------------------------------
__global__ __launch_bounds__(512) void k_ffn12(const unsigned short* __restrict__ tb,
                                               const short* __restrict__ f1wb,
                                               const float* __restrict__ F1b,
                                               const short* __restrict__ f2wb,
                                               const float* __restrict__ F2b,
                                               const float* __restrict__ bn1g,
                                               const float* __restrict__ bn1b,
                                               const float* __restrict__ bnsum1,
                                               const float* __restrict__ bnsq1,
                                               unsigned short* __restrict__ zb,
                                               float* __restrict__ bnsum2,
                                               float* __restrict__ bnsq2) {
    __shared__ unsigned short x_lds[64 * 128];   // 16 KB  (x = bn1(t), bf16)
    __shared__ unsigned short u_lds[64 * 256];   // 32 KB  (full u tile)
    __shared__ float sc_l[128], sh_l[128];

    const int t = threadIdx.x, w = t >> 6, l = t & 63;
    const int g16 = l >> 4, r16 = l & 15;
    const int rowb = blockIdx.x * 64;
    const float inv = 1.f / NN;

    // phase0: bn1 scale/shift per column
    if (t < 128) {
        float mu = bnsum1[t] * inv;
        float var = bnsq1[t] * inv - mu * mu;
        float sc = bn1g[t] * rsqrtf(var + EPSV);
        sc_l[t] = sc;
        sh_l[t] = bn1b[t] - mu * sc;
    }
    __syncthreads();

    // phase1: stage x = bn1(t) into LDS (each thread: 1 row, 16 cols)
    {
        int row = t >> 3, c0 = (t & 7) * 16;
        #pragma unroll
        for (int i = 0; i < 2; ++i) {
            int c = c0 + i * 8;
            bf16x8 v = *(const bf16x8*)(tb + (size_t)(rowb + row) * DD + c);
            bf16x8 xv;
            #pragma unroll
            for (int j = 0; j < 8; ++j)
                xv[j] = (short)f2bf(bf2f((unsigned short)v[j]) * sc_l[c + j] + sh_l[c + j]);
            *(bf16x8*)&x_lds[swz(row, c)] = xv;
        }
    }
    __syncthreads();

    // FFN1 full-width: wave w covers col-tiles {w, w+8} of 16
    f32x4 acc1[4][2];
    #pragma unroll
    for (int rt = 0; rt < 4; ++rt)
        #pragma unroll
        for (int cc = 0; cc < 2; ++cc) acc1[rt][cc] = (f32x4){0.f, 0.f, 0.f, 0.f};
    #pragma unroll
    for (int s = 0; s < 4; ++s) {
        bf16x8 a[4];
        #pragma unroll
        for (int rt = 0; rt < 4; ++rt)
            a[rt] = *(const bf16x8*)&x_lds[swz(rt * 16 + r16, s * 32 + g16 * 8)];
        #pragma unroll
        for (int cc = 0; cc < 2; ++cc) {
            int fc = cc * 8 + w;                 // col-tile (0..15)
            bf16x8 b = *(const bf16x8*)(f1wb + ((size_t)(s * 16 + fc) * 64 + l) * 8);
            #pragma unroll
            for (int rt = 0; rt < 4; ++rt) acc1[rt][cc] = MFMA16(a[rt], b, acc1[rt][cc]);
        }
    }
    #pragma unroll
    for (int cc = 0; cc < 2; ++cc) {
        int colu = (cc * 8 + w) * 16 + r16;      // 0..255
        float fb = F1b[colu];
        #pragma unroll
        for (int rt = 0; rt < 4; ++rt)
            #pragma unroll
            for (int j = 0; j < 4; ++j)
                u_lds[swz256(rt * 16 + g16 * 4 + j, colu)] =
                    f2bf(fmaxf(acc1[rt][cc][j] + fb, 0.f));
    }
    __syncthreads();

    // FFN2 over K=256; wave w computes cols [w*16, w*16+16)
    f32x4 acc2[4];
    #pragma unroll
    for (int rt = 0; rt < 4; ++rt) acc2[rt] = (f32x4){0.f, 0.f, 0.f, 0.f};
    #pragma unroll
    for (int sg = 0; sg < 8; ++sg) {
        bf16x8 a2[4];
        #pragma unroll
        for (int rt = 0; rt < 4; ++rt)
            a2[rt] = *(const bf16x8*)&u_lds[swz256(rt * 16 + r16, sg * 32 + g16 * 8)];
        bf16x8 b = *(const bf16x8*)(f2wb + ((size_t)(sg * 8 + w) * 64 + l) * 8);
        #pragma unroll
        for (int rt = 0; rt < 4; ++rt) acc2[rt] = MFMA16(a2[rt], b, acc2[rt]);
    }

    // epilogue: z = x + acc2 + F2b (bf16 to global); bn2 column sums
    {
        int col = w * 16 + r16;
        float fb = F2b[col];
        float cs = 0.f, cq = 0.f;
        #pragma unroll
        for (int rt = 0; rt < 4; ++rt)
            #pragma unroll
            for (int j = 0; j < 4; ++j) {
                int lr = rt * 16 + g16 * 4 + j;
                float xv = bf2f(x_lds[swz(lr, col)]);
                float zv = xv + acc2[rt][j] + fb;
                zb[(size_t)(rowb + lr) * DD + col] = f2bf(zv);
                cs += zv; cq += zv * zv;
            }
        cs += __shfl_xor(cs, 16); cs += __shfl_xor(cs, 32);
        cq += __shfl_xor(cq, 16); cq += __shfl_xor(cq, 32);
        if (g16 == 0) {
            atomicAdd(&bnsum2[col], cs);
            atomicAdd(&bnsq2[col], cq);
        }
    }
}

// ---------------------------------------------------------------------------
// K5: out = bn2(z) — bf16x8 read, float4 x2 write per thread.
// ---------------------------------------------------------------------------
__global__ __launch_bounds__(256) void k_out(const unsigned short* __restrict__ zb,
                                             const float* __restrict__ bnsum,
                                             const float* __restrict__ bnsq,
                                             const float* __restrict__ gam,
                                             const float* __restrict__ bet,
                                             float* __restrict__ out) {
    int idx = blockIdx.x * 256 + threadIdx.x;  // over N*16 bf16x8 chunks
    int base = idx * 8;
    int c0 = base & 127;
    const float inv = 1.f / NN;
    bf16x8 zv = *(const bf16x8*)(zb + base);
    float o[8];
    #pragma unroll
    for (int j = 0; j < 8; ++j) {
        int c = c0 + j;
        float mu = bnsum[c] * inv;
        float var = bnsq[c] * inv - mu * mu;
        float sc = gam[c] * rsqrtf(var + EPSV);
        float sh = bet[c] - mu * sc;
        o[j] = bf2f((unsigned short)zv[j]) * sc + sh;
    }
    float4 o0 = {o[0], o[1], o[2], o[3]};
    float4 o1 = {o[4], o[5], o[6], o[7]};
    *(float4*)(out + base) = o0;
    *(float4*)(out + base + 4) = o1;
}

// ---------------------------------------------------------------------------
extern "C" void kernel_launch(void* const* d_in, const int* in_sizes, int n_in,
                              void* d_out, int out_size, void* d_ws, size_t ws_size,
                              hipStream_t stream) {
    const float* h    = (const float*)d_in[0];
    const int*   nbr  = (const int*)d_in[1];
    const float* W1   = (const float*)d_in[2];
    const float* b1   = (const float*)d_in[3];
    const float* W2   = (const float*)d_in[4];
    const float* b2   = (const float*)d_in[5];
    const float* OW   = (const float*)d_in[6];
    const float* Ob   = (const float*)d_in[7];
    const float* bn1g = (const float*)d_in[8];
    const float* bn1b = (const float*)d_in[9];
    const float* F1W  = (const float*)d_in[10];
    const float* F1b  = (const float*)d_in[11];
    const float* F2W  = (const float*)d_in[12];
    const float* F2b  = (const float*)d_in[13];
    const float* bn2g = (const float*)d_in[14];
    const float* bn2b = (const float*)d_in[15];
    float* out = (float*)d_out;

    char* wsb = (char*)d_ws;
    unsigned short* gb = (unsigned short*)wsb;                        // 8 MB bf16
    unsigned short* tb = (unsigned short*)(wsb + ((size_t)8 << 20));  // 8 MB bf16
    unsigned short* zb = (unsigned short*)(wsb + ((size_t)16 << 20)); // 8 MB bf16
    char* wtb = wsb + ((size_t)24 << 20);
    short* w1b  = (short*)wtb;                                        // 32 KB
    short* owb  = w1b + 16384;                                        // 64 KB
    short* f1wb = owb + 32768;                                        // 64 KB
    short* f2wb = f1wb + 32768;                                       // 64 KB
    float* stats = (float*)(f2wb + 32768);
    float* bnsum1 = stats;
    float* bnsq1  = stats + 128;
    float* bnsum2 = stats + 256;
    float* bnsq2  = stats + 384;
    float* amean  = stats + 512;           // N floats
    float* amaxv  = amean + NN;            // N floats
    float* aminv  = amaxv + NN;            // N floats

    k_prep<<<10, 256, 0, stream>>>(W1, w1b, stats);
    k_g<<<NN / 64 + 24, 512, 0, stream>>>(h, w1b, gb, OW, F1W, F2W, owb, f1wb, f2wb);
    k_att<<<NN / 4, 256, 0, stream>>>(gb, nbr, b1, W2, b2, amean, amaxv, aminv);
    k_t<<<NN / 64, 512, 0, stream>>>((const short*)owb, h, Ob, amean, amaxv, aminv,
                                     tb, bnsum1, bnsq1);
    k_ffn12<<<NN / 64, 512, 0, stream>>>(tb, (const short*)f1wb, F1b,
                                         (const short*)f2wb, F2b, bn1g, bn1b,
                                         bnsum1, bnsq1, zb, bnsum2, bnsq2);
    k_out<<<NN * 16 / 256, 256, 0, stream>>>(zb, bnsum2, bnsq2, bn2g, bn2b, out);
}

// Round 15
// 75.425 us; speedup vs baseline: 2.1848x; 1.0422x over previous
//
#include <hip/hip_runtime.h>
#include <math.h>

#define NN 32768
#define KK 16
#define DD 128
#define EPSV 1e-5f

typedef __attribute__((ext_vector_type(8))) short bf16x8;
typedef __attribute__((ext_vector_type(4))) float f32x4;

__device__ __forceinline__ unsigned short f2bf(float x) {
    unsigned u; __builtin_memcpy(&u, &x, 4);
    u += 0x7fffu + ((u >> 16) & 1u);          // RNE (finite inputs)
    return (unsigned short)(u >> 16);
}
__device__ __forceinline__ float bf2f(unsigned short b) {
    unsigned u = ((unsigned)b) << 16; float f; __builtin_memcpy(&f, &u, 4); return f;
}

#define MFMA16(a, b, c) __builtin_amdgcn_mfma_f32_16x16x32_bf16((a), (b), (c), 0, 0, 0)

// LDS index swizzle for [64][128] bf16 tiles.
__device__ __forceinline__ int swz(int row, int col) {
    return row * 128 + (col ^ ((row & 7) << 3));
}
// Same swizzle for [64][256] bf16 tiles.
__device__ __forceinline__ int swz256(int row, int col) {
    return row * 256 + (col ^ ((row & 7) << 3));
}

// ---------------------------------------------------------------------------
// K0: small prep — W1 -> bf16 B-fragment order + zero stats.
// ---------------------------------------------------------------------------
__global__ __launch_bounds__(256) void k_prep(const float* __restrict__ W1,
                                              short* __restrict__ w1b,
                                              float* __restrict__ stats) {
    int tid = blockIdx.x * 256 + threadIdx.x;
    if (tid >= 2560) return;
    if (tid >= 2048) { stats[tid - 2048] = 0.f; return; }
    int l = tid & 63, sc = tid >> 6;
    int c = sc & 7, s = sc >> 3;
    int col = c * 16 + (l & 15);
    int k0 = s * 32 + (l >> 4) * 8;
    bf16x8 v;
    #pragma unroll
    for (int j = 0; j < 8; ++j) v[j] = (short)f2bf(W1[(size_t)(k0 + j) * DD + col]);
    *(bf16x8*)(w1b + (size_t)tid * 8) = v;
}

// ---------------------------------------------------------------------------
// K1: gb = bf16(h @ W1). Blocks 0..511: GEMM (8 waves, 64 rows, A from LDS).
// Blocks 512..535: prep OW/F1W/F2W -> bf16 fragment tables (overlaps GEMM).
// ---------------------------------------------------------------------------
__global__ __launch_bounds__(512) void k_g(const float* __restrict__ h,
                                           const short* __restrict__ w1b,
                                           unsigned short* __restrict__ gb,
                                           const float* __restrict__ OW,
                                           const float* __restrict__ F1W,
                                           const float* __restrict__ F2W,
                                           short* __restrict__ owb,
                                           short* __restrict__ f1wb,
                                           short* __restrict__ f2wb) {
    if (blockIdx.x >= NN / 64) {
        int tid = (blockIdx.x - NN / 64) * 512 + threadIdx.x;
        const float* W; short* out; int Ncol;
        if (tid < 4096)      { W = OW;  out = owb;  Ncol = 128; }
        else if (tid < 8192) { W = F1W; out = f1wb; Ncol = 256; tid -= 4096; }
        else                 { W = F2W; out = f2wb; Ncol = 128; tid -= 8192; }
        int l = tid & 63, sc = tid >> 6;
        int NT = Ncol >> 4;
        int c = sc % NT, s = sc / NT;
        int col = c * 16 + (l & 15);
        int k0 = s * 32 + (l >> 4) * 8;
        bf16x8 v;
        #pragma unroll
        for (int j = 0; j < 8; ++j) v[j] = (short)f2bf(W[(size_t)(k0 + j) * Ncol + col]);
        *(bf16x8*)(out + (size_t)tid * 8) = v;
        return;
    }

    __shared__ unsigned short h_lds[64 * 128];   // 16 KB
    const int t = threadIdx.x, w = t >> 6, l = t & 63;
    const int g16 = l >> 4, r16 = l & 15;
    const int rowb = blockIdx.x * 64;

    {
        int row = t >> 3, c0 = (t & 7) * 16;
        #pragma unroll
        for (int i = 0; i < 2; ++i) {
            int c = c0 + i * 8;
            const float* hp = h + (size_t)(rowb + row) * DD + c;
            float4 x0 = *(const float4*)hp;
            float4 x1 = *(const float4*)(hp + 4);
            bf16x8 hv;
            hv[0] = (short)f2bf(x0.x); hv[1] = (short)f2bf(x0.y);
            hv[2] = (short)f2bf(x0.z); hv[3] = (short)f2bf(x0.w);
            hv[4] = (short)f2bf(x1.x); hv[5] = (short)f2bf(x1.y);
            hv[6] = (short)f2bf(x1.z); hv[7] = (short)f2bf(x1.w);
            *(bf16x8*)&h_lds[swz(row, c)] = hv;
        }
    }
    __syncthreads();

    f32x4 acc[4];
    #pragma unroll
    for (int rt = 0; rt < 4; ++rt) acc[rt] = (f32x4){0.f, 0.f, 0.f, 0.f};
    #pragma unroll
    for (int s = 0; s < 4; ++s) {
        bf16x8 a[4];
        #pragma unroll
        for (int rt = 0; rt < 4; ++rt)
            a[rt] = *(const bf16x8*)&h_lds[swz(rt * 16 + r16, s * 32 + g16 * 8)];
        bf16x8 b = *(const bf16x8*)(w1b + ((size_t)(s * 8 + w) * 64 + l) * 8);
        #pragma unroll
        for (int rt = 0; rt < 4; ++rt) acc[rt] = MFMA16(a[rt], b, acc[rt]);
    }
    int col = w * 16 + r16;
    #pragma unroll
    for (int rt = 0; rt < 4; ++rt)
        #pragma unroll
        for (int j = 0; j < 4; ++j)
            gb[(size_t)(rowb + rt * 16 + g16 * 4 + j) * DD + col] = f2bf(acc[rt][j]);
}

// ---------------------------------------------------------------------------
// K2: FUSED attention-stats + t-GEMM. 512 blocks x 8 waves, 64 rows/block.
//  phase A: wave w computes att stats for nodes [w*8, w*8+8) (16-lane groups,
//           identical arithmetic/order to prior k_att) -> LDS
//  phase B: stage aM = bf16(am*h), aS = bf16(sel*h) -> LDS (stats from LDS)
//  phase C: GEMM t = h + [aM||aS] @ OW + Ob; t -> bf16 global; bn1 sums.
// ---------------------------------------------------------------------------
__global__ __launch_bounds__(512) void k_att_t(const unsigned short* __restrict__ gb,
                                               const int* __restrict__ nbr,
                                               const float* __restrict__ b1,
                                               const float* __restrict__ W2,
                                               const float* __restrict__ b2,
                                               const short* __restrict__ owb,
                                               const float* __restrict__ h,
                                               const float* __restrict__ Ob,
                                               unsigned short* __restrict__ tb,
                                               float* __restrict__ bnsum,
                                               float* __restrict__ bnsq) {
    __shared__ unsigned short aM_lds[64 * 128];  // 16 KB
    __shared__ unsigned short aS_lds[64 * 128];  // 16 KB
    __shared__ float am_l[64], ax_l[64], an_l[64];
    const int t = threadIdx.x, w = t >> 6, l = t & 63;
    const int g16 = l >> 4, r16 = l & 15;
    const int rowb = blockIdx.x * 64;

    // ---------- phase A: attention stats for this wave's 8 nodes ----------
    {
        const int grp = l >> 4, r = l & 15;
        float4 b1a = *(const float4*)(b1 + r * 8);
        float4 b1b = *(const float4*)(b1 + r * 8 + 4);
        float4 w2a = *(const float4*)(W2 + r * 8);
        float4 w2b = *(const float4*)(W2 + r * 8 + 4);
        const float b1v[8] = {b1a.x, b1a.y, b1a.z, b1a.w, b1b.x, b1b.y, b1b.z, b1b.w};
        const float w2v[8] = {w2a.x, w2a.y, w2a.z, w2a.w, w2b.x, w2b.y, w2b.z, w2b.w};
        const float b2s = b2[0];
        #pragma unroll 1
        for (int nn = 0; nn < 8; ++nn) {
            int node = rowb + w * 8 + nn;
            bf16x8 gd8 = *(const bf16x8*)((const short*)gb + (size_t)node * DD + r * 8);
            float gd[8];
            #pragma unroll
            for (int j = 0; j < 8; ++j) gd[j] = bf2f((unsigned short)gd8[j]);
            int4 nb4 = *(const int4*)(nbr + node * KK + grp * 4);
            const int srcs[4] = {nb4.x, nb4.y, nb4.z, nb4.w};
            float asum = 0.f, amx = -1e30f, amn = 1e30f;
            #pragma unroll
            for (int it = 0; it < 4; ++it) {
                bf16x8 gs8 = *(const bf16x8*)((const short*)gb + (size_t)srcs[it] * DD + r * 8);
                float v = 0.f;
                #pragma unroll
                for (int j = 0; j < 8; ++j)
                    v += fmaxf(bf2f((unsigned short)gs8[j]) - gd[j] + b1v[j], 0.f) * w2v[j];
                v += __shfl_xor(v, 1); v += __shfl_xor(v, 2);
                v += __shfl_xor(v, 4); v += __shfl_xor(v, 8);
                float s = fmaxf(v + b2s, 0.f);
                float att = __expf(-s);
                asum += att;
                amx = fmaxf(amx, att);
                amn = fminf(amn, att);
            }
            asum += __shfl_xor(asum, 16); asum += __shfl_xor(asum, 32);
            amx = fmaxf(amx, __shfl_xor(amx, 16)); amx = fmaxf(amx, __shfl_xor(amx, 32));
            amn = fminf(amn, __shfl_xor(amn, 16)); amn = fminf(amn, __shfl_xor(amn, 32));
            if (l == 0) {
                am_l[w * 8 + nn] = asum * (1.f / KK);
                ax_l[w * 8 + nn] = amx;
                an_l[w * 8 + nn] = amn;
            }
        }
    }
    __syncthreads();

    // ---------- phase B: stage aM/aS tiles ----------
    {
        int row = t >> 3, c0 = (t & 7) * 16;
        float am = am_l[row], ax = ax_l[row], an = an_l[row];
        #pragma unroll
        for (int i = 0; i < 2; ++i) {
            int c = c0 + i * 8;
            const float* hp = h + (size_t)(rowb + row) * DD + c;
            float4 x0 = *(const float4*)hp;
            float4 x1 = *(const float4*)(hp + 4);
            float v[8] = {x0.x, x0.y, x0.z, x0.w, x1.x, x1.y, x1.z, x1.w};
            bf16x8 m, sfr;
            #pragma unroll
            for (int j = 0; j < 8; ++j) {
                m[j]   = (short)f2bf(am * v[j]);
                sfr[j] = (short)f2bf((v[j] >= 0.f ? ax : an) * v[j]);
            }
            *(bf16x8*)&aM_lds[swz(row, c)] = m;
            *(bf16x8*)&aS_lds[swz(row, c)] = sfr;
        }
    }
    __syncthreads();

    // ---------- phase C: GEMM + epilogue ----------
    f32x4 acc[4];
    #pragma unroll
    for (int rt = 0; rt < 4; ++rt) acc[rt] = (f32x4){0.f, 0.f, 0.f, 0.f};
    #pragma unroll
    for (int s = 0; s < 4; ++s) {
        bf16x8 aM[4], aS[4];
        #pragma unroll
        for (int rt = 0; rt < 4; ++rt) {
            aM[rt] = *(const bf16x8*)&aM_lds[swz(rt * 16 + r16, s * 32 + g16 * 8)];
            aS[rt] = *(const bf16x8*)&aS_lds[swz(rt * 16 + r16, s * 32 + g16 * 8)];
        }
        bf16x8 bM = *(const bf16x8*)(owb + ((size_t)(s * 8 + w) * 64 + l) * 8);
        bf16x8 bS = *(const bf16x8*)(owb + ((size_t)((s + 4) * 8 + w) * 64 + l) * 8);
        #pragma unroll
        for (int rt = 0; rt < 4; ++rt) {
            acc[rt] = MFMA16(aM[rt], bM, acc[rt]);
            acc[rt] = MFMA16(aS[rt], bS, acc[rt]);
        }
    }
    {
        int col = w * 16 + r16;
        float ob = Ob[col];
        float cs = 0.f, cq = 0.f;
        #pragma unroll
        for (int rt = 0; rt < 4; ++rt)
            #pragma unroll
            for (int j = 0; j < 4; ++j) {
                int row = rowb + rt * 16 + g16 * 4 + j;
                size_t idx = (size_t)row * DD + col;
                float tv = h[idx] + acc[rt][j] + ob;
                tb[idx] = f2bf(tv);
                cs += tv; cq += tv * tv;
            }
        cs += __shfl_xor(cs, 16); cs += __shfl_xor(cs, 32);
        cq += __shfl_xor(cq, 16); cq += __shfl_xor(cq, 32);
        if (g16 == 0) {
            atomicAdd(&bnsum[col], cs);
            atomicAdd(&bnsq[col], cq);
        }
    }
}

// ---------------------------------------------------------------------------
// K3: fused FFN1+FFN2. 512 blocks x 8 waves (512 thr), 64 rows/block.
// ---------------------------------------------------------------------------
__global__ __launch_bounds__(512) void k_ffn12(const unsigned short* __restrict__ tb,
                                               const short* __restrict__ f1wb,
                                               const float* __restrict__ F1b,
                                               const short* __restrict__ f2wb,
                                               const float* __restrict__ F2b,
                                               const float* __restrict__ bn1g,
                                               const float* __restrict__ bn1b,
                                               const float* __restrict__ bnsum1,
                                               const float* __restrict__ bnsq1,
                                               unsigned short* __restrict__ zb,
                                               float* __restrict__ bnsum2,
                                               float* __restrict__ bnsq2) {
    __shared__ unsigned short x_lds[64 * 128];   // 16 KB  (x = bn1(t), bf16)
    __shared__ unsigned short u_lds[64 * 256];   // 32 KB  (full u tile)
    __shared__ float sc_l[128], sh_l[128];

    const int t = threadIdx.x, w = t >> 6, l = t & 63;
    const int g16 = l >> 4, r16 = l & 15;
    const int rowb = blockIdx.x * 64;
    const float inv = 1.f / NN;

    if (t < 128) {
        float mu = bnsum1[t] * inv;
        float var = bnsq1[t] * inv - mu * mu;
        float sc = bn1g[t] * rsqrtf(var + EPSV);
        sc_l[t] = sc;
        sh_l[t] = bn1b[t] - mu * sc;
    }
    __syncthreads();

    {
        int row = t >> 3, c0 = (t & 7) * 16;
        #pragma unroll
        for (int i = 0; i < 2; ++i) {
            int c = c0 + i * 8;
            bf16x8 v = *(const bf16x8*)(tb + (size_t)(rowb + row) * DD + c);
            bf16x8 xv;
            #pragma unroll
            for (int j = 0; j < 8; ++j)
                xv[j] = (short)f2bf(bf2f((unsigned short)v[j]) * sc_l[c + j] + sh_l[c + j]);
            *(bf16x8*)&x_lds[swz(row, c)] = xv;
        }
    }
    __syncthreads();

    f32x4 acc1[4][2];
    #pragma unroll
    for (int rt = 0; rt < 4; ++rt)
        #pragma unroll
        for (int cc = 0; cc < 2; ++cc) acc1[rt][cc] = (f32x4){0.f, 0.f, 0.f, 0.f};
    #pragma unroll
    for (int s = 0; s < 4; ++s) {
        bf16x8 a[4];
        #pragma unroll
        for (int rt = 0; rt < 4; ++rt)
            a[rt] = *(const bf16x8*)&x_lds[swz(rt * 16 + r16, s * 32 + g16 * 8)];
        #pragma unroll
        for (int cc = 0; cc < 2; ++cc) {
            int fc = cc * 8 + w;
            bf16x8 b = *(const bf16x8*)(f1wb + ((size_t)(s * 16 + fc) * 64 + l) * 8);
            #pragma unroll
            for (int rt = 0; rt < 4; ++rt) acc1[rt][cc] = MFMA16(a[rt], b, acc1[rt][cc]);
        }
    }
    #pragma unroll
    for (int cc = 0; cc < 2; ++cc) {
        int colu = (cc * 8 + w) * 16 + r16;
        float fb = F1b[colu];
        #pragma unroll
        for (int rt = 0; rt < 4; ++rt)
            #pragma unroll
            for (int j = 0; j < 4; ++j)
                u_lds[swz256(rt * 16 + g16 * 4 + j, colu)] =
                    f2bf(fmaxf(acc1[rt][cc][j] + fb, 0.f));
    }
    __syncthreads();

    f32x4 acc2[4];
    #pragma unroll
    for (int rt = 0; rt < 4; ++rt) acc2[rt] = (f32x4){0.f, 0.f, 0.f, 0.f};
    #pragma unroll
    for (int sg = 0; sg < 8; ++sg) {
        bf16x8 a2[4];
        #pragma unroll
        for (int rt = 0; rt < 4; ++rt)
            a2[rt] = *(const bf16x8*)&u_lds[swz256(rt * 16 + r16, sg * 32 + g16 * 8)];
        bf16x8 b = *(const bf16x8*)(f2wb + ((size_t)(sg * 8 + w) * 64 + l) * 8);
        #pragma unroll
        for (int rt = 0; rt < 4; ++rt) acc2[rt] = MFMA16(a2[rt], b, acc2[rt]);
    }

    {
        int col = w * 16 + r16;
        float fb = F2b[col];
        float cs = 0.f, cq = 0.f;
        #pragma unroll
        for (int rt = 0; rt < 4; ++rt)
            #pragma unroll
            for (int j = 0; j < 4; ++j) {
                int lr = rt * 16 + g16 * 4 + j;
                float xv = bf2f(x_lds[swz(lr, col)]);
                float zv = xv + acc2[rt][j] + fb;
                zb[(size_t)(rowb + lr) * DD + col] = f2bf(zv);
                cs += zv; cq += zv * zv;
            }
        cs += __shfl_xor(cs, 16); cs += __shfl_xor(cs, 32);
        cq += __shfl_xor(cq, 16); cq += __shfl_xor(cq, 32);
        if (g16 == 0) {
            atomicAdd(&bnsum2[col], cs);
            atomicAdd(&bnsq2[col], cq);
        }
    }
}

// ---------------------------------------------------------------------------
// K4: out = bn2(z) — bf16x8 read, float4 x2 write per thread.
// ---------------------------------------------------------------------------
__global__ __launch_bounds__(256) void k_out(const unsigned short* __restrict__ zb,
                                             const float* __restrict__ bnsum,
                                             const float* __restrict__ bnsq,
                                             const float* __restrict__ gam,
                                             const float* __restrict__ bet,
                                             float* __restrict__ out) {
    int idx = blockIdx.x * 256 + threadIdx.x;  // over N*16 bf16x8 chunks
    int base = idx * 8;
    int c0 = base & 127;
    const float inv = 1.f / NN;
    bf16x8 zv = *(const bf16x8*)(zb + base);
    float o[8];
    #pragma unroll
    for (int j = 0; j < 8; ++j) {
        int c = c0 + j;
        float mu = bnsum[c] * inv;
        float var = bnsq[c] * inv - mu * mu;
        float sc = gam[c] * rsqrtf(var + EPSV);
        float sh = bet[c] - mu * sc;
        o[j] = bf2f((unsigned short)zv[j]) * sc + sh;
    }
    float4 o0 = {o[0], o[1], o[2], o[3]};
    float4 o1 = {o[4], o[5], o[6], o[7]};
    *(float4*)(out + base) = o0;
    *(float4*)(out + base + 4) = o1;
}

// ---------------------------------------------------------------------------
extern "C" void kernel_launch(void* const* d_in, const int* in_sizes, int n_in,
                              void* d_out, int out_size, void* d_ws, size_t ws_size,
                              hipStream_t stream) {
    const float* h    = (const float*)d_in[0];
    const int*   nbr  = (const int*)d_in[1];
    const float* W1   = (const float*)d_in[2];
    const float* b1   = (const float*)d_in[3];
    const float* W2   = (const float*)d_in[4];
    const float* b2   = (const float*)d_in[5];
    const float* OW   = (const float*)d_in[6];
    const float* Ob   = (const float*)d_in[7];
    const float* bn1g = (const float*)d_in[8];
    const float* bn1b = (const float*)d_in[9];
    const float* F1W  = (const float*)d_in[10];
    const float* F1b  = (const float*)d_in[11];
    const float* F2W  = (const float*)d_in[12];
    const float* F2b  = (const float*)d_in[13];
    const float* bn2g = (const float*)d_in[14];
    const float* bn2b = (const float*)d_in[15];
    float* out = (float*)d_out;

    char* wsb = (char*)d_ws;
    unsigned short* gb = (unsigned short*)wsb;                        // 8 MB bf16
    unsigned short* tb = (unsigned short*)(wsb + ((size_t)8 << 20));  // 8 MB bf16
    unsigned short* zb = (unsigned short*)(wsb + ((size_t)16 << 20)); // 8 MB bf16
    char* wtb = wsb + ((size_t)24 << 20);
    short* w1b  = (short*)wtb;                                        // 32 KB
    short* owb  = w1b + 16384;                                        // 64 KB
    short* f1wb = owb + 32768;                                        // 64 KB
    short* f2wb = f1wb + 32768;                                       // 64 KB
    float* stats = (float*)(f2wb + 32768);
    float* bnsum1 = stats;
    float* bnsq1  = stats + 128;
    float* bnsum2 = stats + 256;
    float* bnsq2  = stats + 384;

    k_prep<<<10, 256, 0, stream>>>(W1, w1b, stats);
    k_g<<<NN / 64 + 24, 512, 0, stream>>>(h, w1b, gb, OW, F1W, F2W, owb, f1wb, f2wb);
    k_att_t<<<NN / 64, 512, 0, stream>>>(gb, nbr, b1, W2, b2, (const short*)owb,
                                         h, Ob, tb, bnsum1, bnsq1);
    k_ffn12<<<NN / 64, 512, 0, stream>>>(tb, (const short*)f1wb, F1b,
                                         (const short*)f2wb, F2b, bn1g, bn1b,
                                         bnsum1, bnsq1, zb, bnsum2, bnsq2);
    k_out<<<NN * 16 / 256, 256, 0, stream>>>(zb, bnsum2, bnsq2, bn2g, bn2b, out);
}

// Round 16
// 75.108 us; speedup vs baseline: 2.1940x; 1.0042x over previous
//
#include <hip/hip_runtime.h>
#include <math.h>

#define NN 32768
#define KK 16
#define DD 128
#define EPSV 1e-5f

typedef __attribute__((ext_vector_type(8))) short bf16x8;
typedef __attribute__((ext_vector_type(4))) float f32x4;

__device__ __forceinline__ unsigned short f2bf(float x) {
    unsigned u; __builtin_memcpy(&u, &x, 4);
    u += 0x7fffu + ((u >> 16) & 1u);          // RNE (finite inputs)
    return (unsigned short)(u >> 16);
}
__device__ __forceinline__ float bf2f(unsigned short b) {
    unsigned u = ((unsigned)b) << 16; float f; __builtin_memcpy(&f, &u, 4); return f;
}

#define MFMA16(a, b, c) __builtin_amdgcn_mfma_f32_16x16x32_bf16((a), (b), (c), 0, 0, 0)

// LDS index swizzle for [64][128] bf16 tiles.
__device__ __forceinline__ int swz(int row, int col) {
    return row * 128 + (col ^ ((row & 7) << 3));
}
// Same swizzle for [64][256] bf16 tiles.
__device__ __forceinline__ int swz256(int row, int col) {
    return row * 256 + (col ^ ((row & 7) << 3));
}

// ---------------------------------------------------------------------------
// K0: small prep — W1 -> bf16 B-fragment order + zero stats.
// ---------------------------------------------------------------------------
__global__ __launch_bounds__(256) void k_prep(const float* __restrict__ W1,
                                              short* __restrict__ w1b,
                                              float* __restrict__ stats) {
    int tid = blockIdx.x * 256 + threadIdx.x;
    if (tid >= 2560) return;
    if (tid >= 2048) { stats[tid - 2048] = 0.f; return; }
    int l = tid & 63, sc = tid >> 6;
    int c = sc & 7, s = sc >> 3;
    int col = c * 16 + (l & 15);
    int k0 = s * 32 + (l >> 4) * 8;
    bf16x8 v;
    #pragma unroll
    for (int j = 0; j < 8; ++j) v[j] = (short)f2bf(W1[(size_t)(k0 + j) * DD + col]);
    *(bf16x8*)(w1b + (size_t)tid * 8) = v;
}

// ---------------------------------------------------------------------------
// K1: gb = bf16(h @ W1). Blocks 0..511: GEMM (8 waves, 64 rows, A from LDS).
// Blocks 512..535: prep OW/F1W/F2W -> bf16 fragment tables (overlaps GEMM).
// ---------------------------------------------------------------------------
__global__ __launch_bounds__(512) void k_g(const float* __restrict__ h,
                                           const short* __restrict__ w1b,
                                           unsigned short* __restrict__ gb,
                                           const float* __restrict__ OW,
                                           const float* __restrict__ F1W,
                                           const float* __restrict__ F2W,
                                           short* __restrict__ owb,
                                           short* __restrict__ f1wb,
                                           short* __restrict__ f2wb) {
    if (blockIdx.x >= NN / 64) {
        int tid = (blockIdx.x - NN / 64) * 512 + threadIdx.x;
        const float* W; short* out; int Ncol;
        if (tid < 4096)      { W = OW;  out = owb;  Ncol = 128; }
        else if (tid < 8192) { W = F1W; out = f1wb; Ncol = 256; tid -= 4096; }
        else                 { W = F2W; out = f2wb; Ncol = 128; tid -= 8192; }
        int l = tid & 63, sc = tid >> 6;
        int NT = Ncol >> 4;
        int c = sc % NT, s = sc / NT;
        int col = c * 16 + (l & 15);
        int k0 = s * 32 + (l >> 4) * 8;
        bf16x8 v;
        #pragma unroll
        for (int j = 0; j < 8; ++j) v[j] = (short)f2bf(W[(size_t)(k0 + j) * Ncol + col]);
        *(bf16x8*)(out + (size_t)tid * 8) = v;
        return;
    }

    __shared__ unsigned short h_lds[64 * 128];   // 16 KB
    const int t = threadIdx.x, w = t >> 6, l = t & 63;
    const int g16 = l >> 4, r16 = l & 15;
    const int rowb = blockIdx.x * 64;

    {
        int row = t >> 3, c0 = (t & 7) * 16;
        #pragma unroll
        for (int i = 0; i < 2; ++i) {
            int c = c0 + i * 8;
            const float* hp = h + (size_t)(rowb + row) * DD + c;
            float4 x0 = *(const float4*)hp;
            float4 x1 = *(const float4*)(hp + 4);
            bf16x8 hv;
            hv[0] = (short)f2bf(x0.x); hv[1] = (short)f2bf(x0.y);
            hv[2] = (short)f2bf(x0.z); hv[3] = (short)f2bf(x0.w);
            hv[4] = (short)f2bf(x1.x); hv[5] = (short)f2bf(x1.y);
            hv[6] = (short)f2bf(x1.z); hv[7] = (short)f2bf(x1.w);
            *(bf16x8*)&h_lds[swz(row, c)] = hv;
        }
    }
    __syncthreads();

    f32x4 acc[4];
    #pragma unroll
    for (int rt = 0; rt < 4; ++rt) acc[rt] = (f32x4){0.f, 0.f, 0.f, 0.f};
    #pragma unroll
    for (int s = 0; s < 4; ++s) {
        bf16x8 a[4];
        #pragma unroll
        for (int rt = 0; rt < 4; ++rt)
            a[rt] = *(const bf16x8*)&h_lds[swz(rt * 16 + r16, s * 32 + g16 * 8)];
        bf16x8 b = *(const bf16x8*)(w1b + ((size_t)(s * 8 + w) * 64 + l) * 8);
        #pragma unroll
        for (int rt = 0; rt < 4; ++rt) acc[rt] = MFMA16(a[rt], b, acc[rt]);
    }
    int col = w * 16 + r16;
    #pragma unroll
    for (int rt = 0; rt < 4; ++rt)
        #pragma unroll
        for (int j = 0; j < 4; ++j)
            gb[(size_t)(rowb + rt * 16 + g16 * 4 + j) * DD + col] = f2bf(acc[rt][j]);
}

// ---------------------------------------------------------------------------
// K2: FUSED attention-stats + t-GEMM. 512 blocks x 8 waves, 64 rows/block.
//  phase A: wave w computes att stats for nodes [w*8, w*8+8), TWO nodes at a
//           time (doubled outstanding gathers); identical per-node arithmetic.
//  phase B: stage aM = bf16(am*h), aS = bf16(sel*h) -> LDS (stats from LDS)
//  phase C: GEMM t = h + [aM||aS] @ OW + Ob; t -> bf16 global; bn1 sums.
// ---------------------------------------------------------------------------
__global__ __launch_bounds__(512) void k_att_t(const unsigned short* __restrict__ gb,
                                               const int* __restrict__ nbr,
                                               const float* __restrict__ b1,
                                               const float* __restrict__ W2,
                                               const float* __restrict__ b2,
                                               const short* __restrict__ owb,
                                               const float* __restrict__ h,
                                               const float* __restrict__ Ob,
                                               unsigned short* __restrict__ tb,
                                               float* __restrict__ bnsum,
                                               float* __restrict__ bnsq) {
    __shared__ unsigned short aM_lds[64 * 128];  // 16 KB
    __shared__ unsigned short aS_lds[64 * 128];  // 16 KB
    __shared__ float am_l[64], ax_l[64], an_l[64];
    const int t = threadIdx.x, w = t >> 6, l = t & 63;
    const int g16 = l >> 4, r16 = l & 15;
    const int rowb = blockIdx.x * 64;

    // ---------- phase A: attention stats, 2 nodes in flight ----------
    {
        const int grp = l >> 4, r = l & 15;
        float4 b1a = *(const float4*)(b1 + r * 8);
        float4 b1b = *(const float4*)(b1 + r * 8 + 4);
        float4 w2a = *(const float4*)(W2 + r * 8);
        float4 w2b = *(const float4*)(W2 + r * 8 + 4);
        const float b1v[8] = {b1a.x, b1a.y, b1a.z, b1a.w, b1b.x, b1b.y, b1b.z, b1b.w};
        const float w2v[8] = {w2a.x, w2a.y, w2a.z, w2a.w, w2b.x, w2b.y, w2b.z, w2b.w};
        const float b2s = b2[0];
        #pragma unroll 1
        for (int nn = 0; nn < 8; nn += 2) {
            int nodeA = rowb + w * 8 + nn;
            int nodeB = nodeA + 1;
            bf16x8 gdA8 = *(const bf16x8*)((const short*)gb + (size_t)nodeA * DD + r * 8);
            bf16x8 gdB8 = *(const bf16x8*)((const short*)gb + (size_t)nodeB * DD + r * 8);
            int4 nbA = *(const int4*)(nbr + nodeA * KK + grp * 4);
            int4 nbB = *(const int4*)(nbr + nodeB * KK + grp * 4);
            const int srcsA[4] = {nbA.x, nbA.y, nbA.z, nbA.w};
            const int srcsB[4] = {nbB.x, nbB.y, nbB.z, nbB.w};
            float gdA[8], gdB[8];
            #pragma unroll
            for (int j = 0; j < 8; ++j) {
                gdA[j] = bf2f((unsigned short)gdA8[j]);
                gdB[j] = bf2f((unsigned short)gdB8[j]);
            }
            float asumA = 0.f, amxA = -1e30f, amnA = 1e30f;
            float asumB = 0.f, amxB = -1e30f, amnB = 1e30f;
            #pragma unroll
            for (int it = 0; it < 4; ++it) {
                bf16x8 gsA = *(const bf16x8*)((const short*)gb + (size_t)srcsA[it] * DD + r * 8);
                bf16x8 gsB = *(const bf16x8*)((const short*)gb + (size_t)srcsB[it] * DD + r * 8);
                float vA = 0.f, vB = 0.f;
                #pragma unroll
                for (int j = 0; j < 8; ++j) {
                    vA += fmaxf(bf2f((unsigned short)gsA[j]) - gdA[j] + b1v[j], 0.f) * w2v[j];
                    vB += fmaxf(bf2f((unsigned short)gsB[j]) - gdB[j] + b1v[j], 0.f) * w2v[j];
                }
                vA += __shfl_xor(vA, 1); vB += __shfl_xor(vB, 1);
                vA += __shfl_xor(vA, 2); vB += __shfl_xor(vB, 2);
                vA += __shfl_xor(vA, 4); vB += __shfl_xor(vB, 4);
                vA += __shfl_xor(vA, 8); vB += __shfl_xor(vB, 8);
                float sA = fmaxf(vA + b2s, 0.f);
                float sB = fmaxf(vB + b2s, 0.f);
                float attA = __expf(-sA);
                float attB = __expf(-sB);
                asumA += attA; amxA = fmaxf(amxA, attA); amnA = fminf(amnA, attA);
                asumB += attB; amxB = fmaxf(amxB, attB); amnB = fminf(amnB, attB);
            }
            asumA += __shfl_xor(asumA, 16); asumA += __shfl_xor(asumA, 32);
            amxA = fmaxf(amxA, __shfl_xor(amxA, 16)); amxA = fmaxf(amxA, __shfl_xor(amxA, 32));
            amnA = fminf(amnA, __shfl_xor(amnA, 16)); amnA = fminf(amnA, __shfl_xor(amnA, 32));
            asumB += __shfl_xor(asumB, 16); asumB += __shfl_xor(asumB, 32);
            amxB = fmaxf(amxB, __shfl_xor(amxB, 16)); amxB = fmaxf(amxB, __shfl_xor(amxB, 32));
            amnB = fminf(amnB, __shfl_xor(amnB, 16)); amnB = fminf(amnB, __shfl_xor(amnB, 32));
            if (l == 0) {
                am_l[w * 8 + nn] = asumA * (1.f / KK);
                ax_l[w * 8 + nn] = amxA;
                an_l[w * 8 + nn] = amnA;
                am_l[w * 8 + nn + 1] = asumB * (1.f / KK);
                ax_l[w * 8 + nn + 1] = amxB;
                an_l[w * 8 + nn + 1] = amnB;
            }
        }
    }
    __syncthreads();

    // ---------- phase B: stage aM/aS tiles ----------
    {
        int row = t >> 3, c0 = (t & 7) * 16;
        float am = am_l[row], ax = ax_l[row], an = an_l[row];
        #pragma unroll
        for (int i = 0; i < 2; ++i) {
            int c = c0 + i * 8;
            const float* hp = h + (size_t)(rowb + row) * DD + c;
            float4 x0 = *(const float4*)hp;
            float4 x1 = *(const float4*)(hp + 4);
            float v[8] = {x0.x, x0.y, x0.z, x0.w, x1.x, x1.y, x1.z, x1.w};
            bf16x8 m, sfr;
            #pragma unroll
            for (int j = 0; j < 8; ++j) {
                m[j]   = (short)f2bf(am * v[j]);
                sfr[j] = (short)f2bf((v[j] >= 0.f ? ax : an) * v[j]);
            }
            *(bf16x8*)&aM_lds[swz(row, c)] = m;
            *(bf16x8*)&aS_lds[swz(row, c)] = sfr;
        }
    }
    __syncthreads();

    // ---------- phase C: GEMM + epilogue ----------
    f32x4 acc[4];
    #pragma unroll
    for (int rt = 0; rt < 4; ++rt) acc[rt] = (f32x4){0.f, 0.f, 0.f, 0.f};
    #pragma unroll
    for (int s = 0; s < 4; ++s) {
        bf16x8 aM[4], aS[4];
        #pragma unroll
        for (int rt = 0; rt < 4; ++rt) {
            aM[rt] = *(const bf16x8*)&aM_lds[swz(rt * 16 + r16, s * 32 + g16 * 8)];
            aS[rt] = *(const bf16x8*)&aS_lds[swz(rt * 16 + r16, s * 32 + g16 * 8)];
        }
        bf16x8 bM = *(const bf16x8*)(owb + ((size_t)(s * 8 + w) * 64 + l) * 8);
        bf16x8 bS = *(const bf16x8*)(owb + ((size_t)((s + 4) * 8 + w) * 64 + l) * 8);
        #pragma unroll
        for (int rt = 0; rt < 4; ++rt) {
            acc[rt] = MFMA16(aM[rt], bM, acc[rt]);
            acc[rt] = MFMA16(aS[rt], bS, acc[rt]);
        }
    }
    {
        int col = w * 16 + r16;
        float ob = Ob[col];
        float cs = 0.f, cq = 0.f;
        #pragma unroll
        for (int rt = 0; rt < 4; ++rt)
            #pragma unroll
            for (int j = 0; j < 4; ++j) {
                int row = rowb + rt * 16 + g16 * 4 + j;
                size_t idx = (size_t)row * DD + col;
                float tv = h[idx] + acc[rt][j] + ob;
                tb[idx] = f2bf(tv);
                cs += tv; cq += tv * tv;
            }
        cs += __shfl_xor(cs, 16); cs += __shfl_xor(cs, 32);
        cq += __shfl_xor(cq, 16); cq += __shfl_xor(cq, 32);
        if (g16 == 0) {
            atomicAdd(&bnsum[col], cs);
            atomicAdd(&bnsq[col], cq);
        }
    }
}

// ---------------------------------------------------------------------------
// K3: fused FFN1+FFN2. 512 blocks x 8 waves (512 thr), 64 rows/block.
// tb loads hoisted above phase0 so HBM latency hides under the bn1 table.
// ---------------------------------------------------------------------------
__global__ __launch_bounds__(512) void k_ffn12(const unsigned short* __restrict__ tb,
                                               const short* __restrict__ f1wb,
                                               const float* __restrict__ F1b,
                                               const short* __restrict__ f2wb,
                                               const float* __restrict__ F2b,
                                               const float* __restrict__ bn1g,
                                               const float* __restrict__ bn1b,
                                               const float* __restrict__ bnsum1,
                                               const float* __restrict__ bnsq1,
                                               unsigned short* __restrict__ zb,
                                               float* __restrict__ bnsum2,
                                               float* __restrict__ bnsq2) {
    __shared__ unsigned short x_lds[64 * 128];   // 16 KB  (x = bn1(t), bf16)
    __shared__ unsigned short u_lds[64 * 256];   // 32 KB  (full u tile)
    __shared__ float sc_l[128], sh_l[128];

    const int t = threadIdx.x, w = t >> 6, l = t & 63;
    const int g16 = l >> 4, r16 = l & 15;
    const int rowb = blockIdx.x * 64;
    const float inv = 1.f / NN;

    // prefetch this thread's tb chunk (latency hides under phase0)
    const int prow = t >> 3, pc0 = (t & 7) * 16;
    bf16x8 tv0 = *(const bf16x8*)(tb + (size_t)(rowb + prow) * DD + pc0);
    bf16x8 tv1 = *(const bf16x8*)(tb + (size_t)(rowb + prow) * DD + pc0 + 8);

    // phase0: bn1 scale/shift per column
    if (t < 128) {
        float mu = bnsum1[t] * inv;
        float var = bnsq1[t] * inv - mu * mu;
        float sc = bn1g[t] * rsqrtf(var + EPSV);
        sc_l[t] = sc;
        sh_l[t] = bn1b[t] - mu * sc;
    }
    __syncthreads();

    // phase1: convert prefetched t -> x and store to LDS
    {
        bf16x8 xv0, xv1;
        #pragma unroll
        for (int j = 0; j < 8; ++j) {
            xv0[j] = (short)f2bf(bf2f((unsigned short)tv0[j]) * sc_l[pc0 + j] + sh_l[pc0 + j]);
            xv1[j] = (short)f2bf(bf2f((unsigned short)tv1[j]) * sc_l[pc0 + 8 + j] + sh_l[pc0 + 8 + j]);
        }
        *(bf16x8*)&x_lds[swz(prow, pc0)] = xv0;
        *(bf16x8*)&x_lds[swz(prow, pc0 + 8)] = xv1;
    }
    __syncthreads();

    f32x4 acc1[4][2];
    #pragma unroll
    for (int rt = 0; rt < 4; ++rt)
        #pragma unroll
        for (int cc = 0; cc < 2; ++cc) acc1[rt][cc] = (f32x4){0.f, 0.f, 0.f, 0.f};
    #pragma unroll
    for (int s = 0; s < 4; ++s) {
        bf16x8 a[4];
        #pragma unroll
        for (int rt = 0; rt < 4; ++rt)
            a[rt] = *(const bf16x8*)&x_lds[swz(rt * 16 + r16, s * 32 + g16 * 8)];
        #pragma unroll
        for (int cc = 0; cc < 2; ++cc) {
            int fc = cc * 8 + w;
            bf16x8 b = *(const bf16x8*)(f1wb + ((size_t)(s * 16 + fc) * 64 + l) * 8);
            #pragma unroll
            for (int rt = 0; rt < 4; ++rt) acc1[rt][cc] = MFMA16(a[rt], b, acc1[rt][cc]);
        }
    }
    #pragma unroll
    for (int cc = 0; cc < 2; ++cc) {
        int colu = (cc * 8 + w) * 16 + r16;
        float fb = F1b[colu];
        #pragma unroll
        for (int rt = 0; rt < 4; ++rt)
            #pragma unroll
            for (int j = 0; j < 4; ++j)
                u_lds[swz256(rt * 16 + g16 * 4 + j, colu)] =
                    f2bf(fmaxf(acc1[rt][cc][j] + fb, 0.f));
    }
    __syncthreads();

    f32x4 acc2[4];
    #pragma unroll
    for (int rt = 0; rt < 4; ++rt) acc2[rt] = (f32x4){0.f, 0.f, 0.f, 0.f};
    #pragma unroll
    for (int sg = 0; sg < 8; ++sg) {
        bf16x8 a2[4];
        #pragma unroll
        for (int rt = 0; rt < 4; ++rt)
            a2[rt] = *(const bf16x8*)&u_lds[swz256(rt * 16 + r16, sg * 32 + g16 * 8)];
        bf16x8 b = *(const bf16x8*)(f2wb + ((size_t)(sg * 8 + w) * 64 + l) * 8);
        #pragma unroll
        for (int rt = 0; rt < 4; ++rt) acc2[rt] = MFMA16(a2[rt], b, acc2[rt]);
    }

    {
        int col = w * 16 + r16;
        float fb = F2b[col];
        float cs = 0.f, cq = 0.f;
        #pragma unroll
        for (int rt = 0; rt < 4; ++rt)
            #pragma unroll
            for (int j = 0; j < 4; ++j) {
                int lr = rt * 16 + g16 * 4 + j;
                float xv = bf2f(x_lds[swz(lr, col)]);
                float zv = xv + acc2[rt][j] + fb;
                zb[(size_t)(rowb + lr) * DD + col] = f2bf(zv);
                cs += zv; cq += zv * zv;
            }
        cs += __shfl_xor(cs, 16); cs += __shfl_xor(cs, 32);
        cq += __shfl_xor(cq, 16); cq += __shfl_xor(cq, 32);
        if (g16 == 0) {
            atomicAdd(&bnsum2[col], cs);
            atomicAdd(&bnsq2[col], cq);
        }
    }
}

// ---------------------------------------------------------------------------
// K4: out = bn2(z) — bf16x8 read, float4 x2 write per thread.
// ---------------------------------------------------------------------------
__global__ __launch_bounds__(256) void k_out(const unsigned short* __restrict__ zb,
                                             const float* __restrict__ bnsum,
                                             const float* __restrict__ bnsq,
                                             const float* __restrict__ gam,
                                             const float* __restrict__ bet,
                                             float* __restrict__ out) {
    int idx = blockIdx.x * 256 + threadIdx.x;  // over N*16 bf16x8 chunks
    int base = idx * 8;
    int c0 = base & 127;
    const float inv = 1.f / NN;
    bf16x8 zv = *(const bf16x8*)(zb + base);
    float o[8];
    #pragma unroll
    for (int j = 0; j < 8; ++j) {
        int c = c0 + j;
        float mu = bnsum[c] * inv;
        float var = bnsq[c] * inv - mu * mu;
        float sc = gam[c] * rsqrtf(var + EPSV);
        float sh = bet[c] - mu * sc;
        o[j] = bf2f((unsigned short)zv[j]) * sc + sh;
    }
    float4 o0 = {o[0], o[1], o[2], o[3]};
    float4 o1 = {o[4], o[5], o[6], o[7]};
    *(float4*)(out + base) = o0;
    *(float4*)(out + base + 4) = o1;
}

// ---------------------------------------------------------------------------
extern "C" void kernel_launch(void* const* d_in, const int* in_sizes, int n_in,
                              void* d_out, int out_size, void* d_ws, size_t ws_size,
                              hipStream_t stream) {
    const float* h    = (const float*)d_in[0];
    const int*   nbr  = (const int*)d_in[1];
    const float* W1   = (const float*)d_in[2];
    const float* b1   = (const float*)d_in[3];
    const float* W2   = (const float*)d_in[4];
    const float* b2   = (const float*)d_in[5];
    const float* OW   = (const float*)d_in[6];
    const float* Ob   = (const float*)d_in[7];
    const float* bn1g = (const float*)d_in[8];
    const float* bn1b = (const float*)d_in[9];
    const float* F1W  = (const float*)d_in[10];
    const float* F1b  = (const float*)d_in[11];
    const float* F2W  = (const float*)d_in[12];
    const float* F2b  = (const float*)d_in[13];
    const float* bn2g = (const float*)d_in[14];
    const float* bn2b = (const float*)d_in[15];
    float* out = (float*)d_out;

    char* wsb = (char*)d_ws;
    unsigned short* gb = (unsigned short*)wsb;                        // 8 MB bf16
    unsigned short* tb = (unsigned short*)(wsb + ((size_t)8 << 20));  // 8 MB bf16
    unsigned short* zb = (unsigned short*)(wsb + ((size_t)16 << 20)); // 8 MB bf16
    char* wtb = wsb + ((size_t)24 << 20);
    short* w1b  = (short*)wtb;                                        // 32 KB
    short* owb  = w1b + 16384;                                        // 64 KB
    short* f1wb = owb + 32768;                                        // 64 KB
    short* f2wb = f1wb + 32768;                                       // 64 KB
    float* stats = (float*)(f2wb + 32768);
    float* bnsum1 = stats;
    float* bnsq1  = stats + 128;
    float* bnsum2 = stats + 256;
    float* bnsq2  = stats + 384;

    k_prep<<<10, 256, 0, stream>>>(W1, w1b, stats);
    k_g<<<NN / 64 + 24, 512, 0, stream>>>(h, w1b, gb, OW, F1W, F2W, owb, f1wb, f2wb);
    k_att_t<<<NN / 64, 512, 0, stream>>>(gb, nbr, b1, W2, b2, (const short*)owb,
                                         h, Ob, tb, bnsum1, bnsq1);
    k_ffn12<<<NN / 64, 512, 0, stream>>>(tb, (const short*)f1wb, F1b,
                                         (const short*)f2wb, F2b, bn1g, bn1b,
                                         bnsum1, bnsq1, zb, bnsum2, bnsq2);
    k_out<<<NN * 16 / 256, 256, 0, stream>>>(zb, bnsum2, bnsq2, bn2g, bn2b, out);
}